// Round 4
// baseline (958.525 us; speedup 1.0000x reference)
//
#include <hip/hip_runtime.h>
#include <math.h>
#include <stdint.h>

#define N_TOK 16384
#define DIM   2048
#define NEXP  64
#define TOPK  8

#define BM 128
#define BN 128
#define BKE 32          // k-elements per iteration

typedef _Float16 half8 __attribute__((ext_vector_type(8)));
typedef float    f32x4 __attribute__((ext_vector_type(4)));

#define GLOBAL_AS __attribute__((address_space(1)))
#define LDS_AS    __attribute__((address_space(3)))

#define LO_SCALE     4096.0f
#define INV_LO_SCALE (1.0f / 4096.0f)

// pack fp32 v -> u32: low16 = fp16(v), high16 = fp16((v - fp16(v)) * 4096)
__device__ inline uint32_t pack_split(float v) {
    _Float16 hi = (_Float16)v;
    float r = (v - (float)hi) * LO_SCALE;
    _Float16 lo = (_Float16)r;
    return (uint32_t)__builtin_bit_cast(uint16_t, hi) |
           ((uint32_t)__builtin_bit_cast(uint16_t, lo) << 16);
}

__device__ inline _Float16 split_hi(float v) { return (_Float16)v; }
__device__ inline _Float16 split_lo(float v) {
    _Float16 hi = (_Float16)v;
    return (_Float16)((v - (float)hi) * LO_SCALE);
}

union U4H8 { uint32_t u[4]; half8 h; };

// packed-u32 fragment loader (fallback path + epilogue W2 reads)
__device__ inline void load_frag(const uint32_t* base, int row, int quad,
                                 half8& hi, half8& lo) {
    const int sw = row & 7;
    const uint4 q0 = *(const uint4*)(base + row * 32 + (((quad * 2)     ^ sw) << 2));
    const uint4 q1 = *(const uint4*)(base + row * 32 + (((quad * 2 + 1) ^ sw) << 2));
    uint32_t u[8] = {q0.x, q0.y, q0.z, q0.w, q1.x, q1.y, q1.z, q1.w};
    U4H8 H, L;
    #pragma unroll
    for (int j = 0; j < 4; j++) {
        H.u[j] = (u[2 * j] & 0xffffu) | (u[2 * j + 1] << 16);
        L.u[j] = (u[2 * j] >> 16)     | (u[2 * j + 1] & 0xffff0000u);
    }
    hi = H.h; lo = L.h;
}

// split-array A fragment loader: LDS row = 64 halves = [32 hi | 32 lo]
// = 8 slots of 16B; logical chunk c lives at slot c ^ (row&7).
__device__ inline void load_frag2(const _Float16* base, int row, int quad,
                                  half8& hi, half8& lo) {
    const int sw = row & 7;
    hi = *(const half8*)(base + row * 64 + ((quad       ^ sw) << 3));
    lo = *(const half8*)(base + row * 64 + (((quad + 4) ^ sw) << 3));
}

// ---------------------------------------------------------------------------
// fused conversion kernel: block-range dispatch over {x-split, W1T-split, W2T}
// ---------------------------------------------------------------------------
#define CVT_XBLKS  ((N_TOK * DIM) / (256 * 8))            // 16384
#define CVT_W1BLKS ((DIM / 32) * (DIM / 32))              // 4096
#define CVT_W2BLKS ((NEXP * DIM) / 256)                   // 512

__global__ __launch_bounds__(256) void convert_all(
    const float* __restrict__ x, const float* __restrict__ W1,
    const float* __restrict__ W2,
    _Float16* __restrict__ xhi, _Float16* __restrict__ xlo,
    _Float16* __restrict__ w1hi, _Float16* __restrict__ w1lo,
    uint32_t* __restrict__ W2Tp)
{
    const int b = blockIdx.x;
    if (b < CVT_XBLKS) {
        size_t i = ((size_t)b * 256 + threadIdx.x) * 8;
        float4 v0 = *(const float4*)(x + i);
        float4 v1 = *(const float4*)(x + i + 4);
        const float vv[8] = {v0.x, v0.y, v0.z, v0.w, v1.x, v1.y, v1.z, v1.w};
        half8 h, l;
        #pragma unroll
        for (int j = 0; j < 8; j++) { h[j] = split_hi(vv[j]); l[j] = split_lo(vv[j]); }
        *(half8*)(xhi + i) = h;
        *(half8*)(xlo + i) = l;
    } else if (b < CVT_XBLKS + CVT_W1BLKS) {
        __shared__ float s[32][33];
        const int bb = b - CVT_XBLKS;
        const int n0 = (bb & 63) * 32, k0 = (bb >> 6) * 32;
        const int tr = threadIdx.x & 31, tc = threadIdx.x >> 5;   // 32 x 8
        #pragma unroll
        for (int r = 0; r < 4; r++) {
            int row = tc + r * 8;
            s[row][tr] = W1[(size_t)(k0 + row) * DIM + n0 + tr];
        }
        __syncthreads();
        #pragma unroll
        for (int r = 0; r < 4; r++) {
            int row = tc + r * 8;                                 // n-local
            float v = s[tr][row];
            w1hi[(size_t)(n0 + row) * DIM + k0 + tr] = split_hi(v);
            w1lo[(size_t)(n0 + row) * DIM + k0 + tr] = split_lo(v);
        }
    } else {
        const int i = (b - CVT_XBLKS - CVT_W1BLKS) * 256 + threadIdx.x;
        const int e = i >> 11, n = i & 2047;
        W2Tp[i] = pack_split(W2[(size_t)n * NEXP + e]);
    }
}

// in-place packed converter (mid-fallback path)
__global__ __launch_bounds__(256) void convert_x_inplace(float* __restrict__ x) {
    size_t i = ((size_t)blockIdx.x * 256 + threadIdx.x) * 4;
    float4 v = *(const float4*)(x + i);
    uint4 p;
    p.x = pack_split(v.x); p.y = pack_split(v.y);
    p.z = pack_split(v.z); p.w = pack_split(v.w);
    *(uint4*)(x + i) = p;
}

__global__ __launch_bounds__(256) void convert_w1t_packed(
    const float* __restrict__ W1, uint32_t* __restrict__ W1Tp)
{
    __shared__ float s[32][33];
    const int k0 = blockIdx.y * 32, n0 = blockIdx.x * 32;
    const int tr = threadIdx.x & 31, tc = threadIdx.x >> 5;
    #pragma unroll
    for (int r = 0; r < 4; r++) {
        int row = tc + r * 8;
        s[row][tr] = W1[(size_t)(k0 + row) * DIM + n0 + tr];
    }
    __syncthreads();
    #pragma unroll
    for (int r = 0; r < 4; r++) {
        int row = tc + r * 8;
        W1Tp[(size_t)(n0 + row) * DIM + k0 + tr] = pack_split(s[tr][row]);
    }
}

__global__ __launch_bounds__(256) void convert_w2t_packed(
    const float* __restrict__ W2, uint32_t* __restrict__ W2Tp) {
    int i = blockIdx.x * 256 + threadIdx.x;   // over 64*2048
    int e = i >> 11, n = i & 2047;
    W2Tp[i] = pack_split(W2[(size_t)n * NEXP + e]);
}

// ---------------------------------------------------------------------------
// fused GEMM v6: B (W1T) fragments read DIRECTLY from global (L2-hot via the
// 8-block n-swizzle group) into registers; only A (tokens) is LDS-staged.
// Rationale (R3 post-mortem): LDS pipe per CU per K-step was reads 1536 +
// writes 600 ≈ 2140 cy vs MFMA 1862 cy — co-equal long poles, fully
// serialized at 4270 cy/step regardless of barrier schedule. Removing B from
// LDS cuts the LDS pipe to ~1070 cy; MFMA becomes the single long pole.
// VMEM bookkeeping: exactly 12 VMEM ops per step (4 A-stage global_load_lds
// + 8 B dwordx4 loads), all fenced between volatile asm waits, so
// vmcnt(12) at step k waits exactly tile-k's A staging; compiler's own
// waits cover B register uses.
// ---------------------------------------------------------------------------

#define MFMA_F16(a_, b_, c_) __builtin_amdgcn_mfma_f32_16x16x32_f16(a_, b_, c_, 0, 0, 0)

#define LOADB(koff_)                                                            \
    _Pragma("unroll")                                                           \
    for (int nt = 0; nt < 4; nt++) {                                            \
        bh[nt] = *(const half8*)(bH + (size_t)nt * NTS + (koff_));              \
        bl[nt] = *(const half8*)(bL + (size_t)nt * NTS + (koff_));              \
    }

// one K-step: A from (ASrc), B(koff) from global; optionally stage A(k+1)->ASt
#define KSTEP(ASrc_, ASt_, koff_, DOSTAGE_)                                     \
    {                                                                           \
        if (DOSTAGE_) {                                                         \
            _Pragma("unroll")                                                   \
            for (int r = 0; r < 4; r++) {                                       \
                const int wslot = (r * 256 + wid * 64) << 2;                    \
                __builtin_amdgcn_global_load_lds(                               \
                    (const GLOBAL_AS uint32_t*)gA[r],                           \
                    (LDS_AS uint32_t*)((ASt_) + wslot), 16, 0, 0);              \
                gA[r] += BKE;                                                   \
            }                                                                   \
        }                                                                       \
        half8 bh[4], bl[4];                                                     \
        LOADB(koff_)                                                            \
        if (DOSTAGE_) {                                                         \
            /* wait tile-k A staged; leave this step's 12 ops in flight */      \
            asm volatile("s_waitcnt vmcnt(12)" ::: "memory");                   \
        } else {                                                                \
            /* last step: only this step's 8 B loads may remain */              \
            asm volatile("s_waitcnt vmcnt(8)" ::: "memory");                    \
        }                                                                       \
        __builtin_amdgcn_s_barrier();                                           \
        half8 ah[4], al[4];                                                     \
        _Pragma("unroll")                                                       \
        for (int mt = 0; mt < 4; mt++)                                          \
            load_frag2((const _Float16*)(ASrc_), wm + mt * 16 + l16, quad,      \
                       ah[mt], al[mt]);                                         \
        __builtin_amdgcn_s_setprio(1);                                          \
        _Pragma("unroll")                                                       \
        for (int mt = 0; mt < 4; mt++)                                          \
            _Pragma("unroll")                                                   \
            for (int nt = 0; nt < 4; nt++) {                                    \
                am[mt][nt] = MFMA_F16(ah[mt], bh[nt], am[mt][nt]);              \
                ac[mt][nt] = MFMA_F16(ah[mt], bl[nt], ac[mt][nt]);              \
                ac[mt][nt] = MFMA_F16(al[mt], bh[nt], ac[mt][nt]);              \
            }                                                                   \
        __builtin_amdgcn_s_setprio(0);                                          \
        asm volatile("s_waitcnt lgkmcnt(0)" ::: "memory");                      \
        __builtin_amdgcn_s_barrier();   /* A buf now safe to restage */         \
    }

__global__ __launch_bounds__(256, 2) void gemm_fused_v2(
    const _Float16* __restrict__ xhi, const _Float16* __restrict__ xlo,
    const _Float16* __restrict__ w1hi, const _Float16* __restrict__ w1lo,
    const float* __restrict__ b1, const uint32_t* __restrict__ W2Tp,
    float* __restrict__ Lp)
{
    __shared__ uint32_t smem[16384];          // 64 KB (Hs epilogue needs it all)
    uint32_t* A0 = smem;                      // A tile [128][64] halves, 16 KB
    uint32_t* A1 = smem + 4096;               // double-buffer partner

    const int t    = threadIdx.x;
    const int wid  = t >> 6;
    const int lane = t & 63;
    const int quad = lane >> 4;
    const int l16  = lane & 15;

    // block swizzle: groups of 8 m-blocks share one n-block (W1T slice L2 reuse)
    const int lin = blockIdx.x;               // 2048 blocks
    const int grp = lin >> 7;
    const int rem = lin & 127;
    const int m0 = (grp * 8 + (rem & 7)) * BM;
    const int n0 = (rem >> 3) * BN;

    // A staging source pointers; LDS slot s of row r holds logical chunk
    // c = s ^ (r&7); c<4 -> hi array chunk c, else lo array chunk c-4.
    const _Float16* gA[4];
    #pragma unroll
    for (int r = 0; r < 4; r++) {
        int s_lin = r * 256 + t;
        int row = s_lin >> 3;
        int c   = (s_lin & 7) ^ (row & 7);
        gA[r] = (c < 4) ? xhi + (size_t)(m0 + row) * DIM + c * 8
                        : xlo + (size_t)(m0 + row) * DIM + (c - 4) * 8;
    }

    const int wm = (wid & 1) * 64;
    const int wn = (wid >> 1) * 64;

    // B fragment base pointers (per lane, nt=0): 16B contiguous per lane,
    // 4 lanes (quad) per row -> full 64B sectors, L1/L2-served.
    const size_t NTS = (size_t)16 * DIM;      // nt row stride in halves
    const _Float16* bH = w1hi + (size_t)(n0 + wn + l16) * DIM + quad * 8;
    const _Float16* bL = w1lo + (size_t)(n0 + wn + l16) * DIM + quad * 8;

    f32x4 am[4][4], ac[4][4];
    #pragma unroll
    for (int i = 0; i < 4; i++)
        #pragma unroll
        for (int j = 0; j < 4; j++) { am[i][j] = (f32x4)0.0f; ac[i][j] = (f32x4)0.0f; }

    // prologue: stage A tile 0 into A0 (4 loads in flight)
    #pragma unroll
    for (int r = 0; r < 4; r++) {
        const int wslot = (r * 256 + wid * 64) << 2;
        __builtin_amdgcn_global_load_lds((const GLOBAL_AS uint32_t*)gA[r],
                                         (LDS_AS uint32_t*)(A0 + wslot), 16, 0, 0);
        gA[r] += BKE;
    }

    // 64 K-steps as 32 pairs; A buffers alternate with static addresses.
    for (int kp = 0; kp < 32; kp++) {
        KSTEP(A0, A1, (size_t)(2 * kp)     * BKE, true);
        KSTEP(A1, A0, (size_t)(2 * kp + 1) * BKE, kp != 31);
    }

    // ---- epilogue: bias + exact GELU, pack h into swizzled LDS [128][128] ----
    uint32_t* Hs = smem;
    #pragma unroll
    for (int mt = 0; mt < 4; mt++)
        #pragma unroll
        for (int nt = 0; nt < 4; nt++) {
            const int coln = wn + nt * 16 + l16;
            const float b1v = b1[n0 + coln];
            #pragma unroll
            for (int r = 0; r < 4; r++) {
                float h = am[mt][nt][r] + ac[mt][nt][r] * INV_LO_SCALE + b1v;
                h = 0.5f * h * (1.0f + erff(h * 0.70710678118654752440f));
                const int rowm = wm + mt * 16 + quad * 4 + r;
                const int word = rowm * 128 + ((((coln >> 2) ^ (rowm & 7)) << 2) | (coln & 3));
                Hs[word] = pack_split(h);
            }
        }
    __syncthreads();

    // ---- GEMM2: logits[128 x 64] = h[128 x 128] @ W2T' (4 K=32 steps) ----
    f32x4 a2m[2][4], a2c[2][4];
    #pragma unroll
    for (int i = 0; i < 2; i++)
        #pragma unroll
        for (int j = 0; j < 4; j++) { a2m[i][j] = (f32x4)0.0f; a2c[i][j] = (f32x4)0.0f; }

    #pragma unroll
    for (int ks = 0; ks < 4; ks++) {
        half8 a2h[2], a2l[2];
        #pragma unroll
        for (int mt2 = 0; mt2 < 2; mt2++) {
            const int row = wid * 32 + mt2 * 16 + l16;
            const int sw  = row & 7;
            const int cb  = ks * 8 + quad * 2;           // k = ks*32 + quad*8 + j
            const uint4 q0 = *(const uint4*)(Hs + row * 128 + ((cb ^ sw) << 2));
            const uint4 q1 = *(const uint4*)(Hs + row * 128 + (((cb + 1) ^ sw) << 2));
            uint32_t u[8] = {q0.x, q0.y, q0.z, q0.w, q1.x, q1.y, q1.z, q1.w};
            U4H8 H, L;
            #pragma unroll
            for (int j = 0; j < 4; j++) {
                H.u[j] = (u[2 * j] & 0xffffu) | (u[2 * j + 1] << 16);
                L.u[j] = (u[2 * j] >> 16)     | (u[2 * j + 1] & 0xffff0000u);
            }
            a2h[mt2] = H.h; a2l[mt2] = L.h;
        }
        #pragma unroll
        for (int et = 0; et < 4; et++) {
            const int e = et * 16 + l16;
            const uint32_t* wp = W2Tp + (size_t)e * DIM + n0 + ks * 32 + quad * 8;
            const uint4 q0 = *(const uint4*)wp;
            const uint4 q1 = *(const uint4*)(wp + 4);
            uint32_t u[8] = {q0.x, q0.y, q0.z, q0.w, q1.x, q1.y, q1.z, q1.w};
            U4H8 H, L;
            #pragma unroll
            for (int j = 0; j < 4; j++) {
                H.u[j] = (u[2 * j] & 0xffffu) | (u[2 * j + 1] << 16);
                L.u[j] = (u[2 * j] >> 16)     | (u[2 * j + 1] & 0xffff0000u);
            }
            #pragma unroll
            for (int mt2 = 0; mt2 < 2; mt2++) {
                a2m[mt2][et] = MFMA_F16(a2h[mt2], H.h, a2m[mt2][et]);
                a2c[mt2][et] = MFMA_F16(a2h[mt2], L.h, a2c[mt2][et]);
                a2c[mt2][et] = MFMA_F16(a2l[mt2], H.h, a2c[mt2][et]);
            }
        }
    }

    #pragma unroll
    for (int mt2 = 0; mt2 < 2; mt2++)
        #pragma unroll
        for (int et = 0; et < 4; et++)
            #pragma unroll
            for (int r = 0; r < 4; r++) {
                const float lg = a2m[mt2][et][r] + a2c[mt2][et][r] * INV_LO_SCALE;
                const int rowm = m0 + wid * 32 + mt2 * 16 + quad * 4 + r;
                const int e = et * 16 + l16;
                atomicAdd(&Lp[(size_t)rowm * NEXP + e], lg);
            }
}

// ---------------------------------------------------------------------------
// packed-u32 fused GEMM (mid fallback, needs only ~21 MB ws)
// ---------------------------------------------------------------------------
__global__ __launch_bounds__(256, 2) void gemm_fused(
    const uint32_t* __restrict__ xp, const uint32_t* __restrict__ W1Tp,
    const float* __restrict__ b1, const uint32_t* __restrict__ W2Tp,
    float* __restrict__ Lp)
{
    __shared__ uint32_t smem[16384];
    uint32_t* Ap = smem;
    uint32_t* Bp = smem + 4096;

    const int t    = threadIdx.x;
    const int wid  = t >> 6;
    const int lane = t & 63;
    const int quad = lane >> 4;
    const int l16  = lane & 15;

    const int lin = blockIdx.x;
    const int grp = lin >> 7;
    const int rem = lin & 127;
    const int m0 = (grp * 8 + (rem & 7)) * BM;
    const int n0 = (rem >> 3) * BN;

    const uint32_t* gA[4];
    const uint32_t* gB[4];
    #pragma unroll
    for (int r = 0; r < 4; r++) {
        int s = r * 256 + t;
        int row = s >> 3;
        int c   = s & 7;
        int co  = (c ^ (row & 7)) << 2;
        gA[r] = xp   + (size_t)(m0 + row) * DIM + co;
        gB[r] = W1Tp + (size_t)(n0 + row) * DIM + co;
    }

    f32x4 am[4][4], ac[4][4];
    #pragma unroll
    for (int i = 0; i < 4; i++)
        #pragma unroll
        for (int j = 0; j < 4; j++) { am[i][j] = (f32x4)0.0f; ac[i][j] = (f32x4)0.0f; }

    const int wm = (wid & 1) * 64;
    const int wn = (wid >> 1) * 64;

    for (int k0 = 0; k0 < DIM; k0 += BKE) {
        #pragma unroll
        for (int r = 0; r < 4; r++) {
            const int wslot = (r * 256 + wid * 64) << 2;
            __builtin_amdgcn_global_load_lds((const GLOBAL_AS uint32_t*)gA[r],
                                             (LDS_AS uint32_t*)(Ap + wslot), 16, 0, 0);
            __builtin_amdgcn_global_load_lds((const GLOBAL_AS uint32_t*)gB[r],
                                             (LDS_AS uint32_t*)(Bp + wslot), 16, 0, 0);
            gA[r] += BKE; gB[r] += BKE;
        }
        __syncthreads();

        half8 ah[4], al[4], bh[4], bl[4];
        #pragma unroll
        for (int mt = 0; mt < 4; mt++)
            load_frag(Ap, wm + mt * 16 + l16, quad, ah[mt], al[mt]);
        #pragma unroll
        for (int nt = 0; nt < 4; nt++)
            load_frag(Bp, wn + nt * 16 + l16, quad, bh[nt], bl[nt]);

        #pragma unroll
        for (int mt = 0; mt < 4; mt++)
            #pragma unroll
            for (int nt = 0; nt < 4; nt++) {
                am[mt][nt] = MFMA_F16(ah[mt], bh[nt], am[mt][nt]);
                ac[mt][nt] = MFMA_F16(ah[mt], bl[nt], ac[mt][nt]);
                ac[mt][nt] = MFMA_F16(al[mt], bh[nt], ac[mt][nt]);
            }
        __syncthreads();
    }

    uint32_t* Hs = smem;
    #pragma unroll
    for (int mt = 0; mt < 4; mt++)
        #pragma unroll
        for (int nt = 0; nt < 4; nt++) {
            const int coln = wn + nt * 16 + l16;
            const float b1v = b1[n0 + coln];
            #pragma unroll
            for (int r = 0; r < 4; r++) {
                float h = am[mt][nt][r] + ac[mt][nt][r] * INV_LO_SCALE + b1v;
                h = 0.5f * h * (1.0f + erff(h * 0.70710678118654752440f));
                const int rowm = wm + mt * 16 + quad * 4 + r;
                const int word = rowm * 128 + ((((coln >> 2) ^ (rowm & 7)) << 2) | (coln & 3));
                Hs[word] = pack_split(h);
            }
        }
    __syncthreads();

    f32x4 a2m[2][4], a2c[2][4];
    #pragma unroll
    for (int i = 0; i < 2; i++)
        #pragma unroll
        for (int j = 0; j < 4; j++) { a2m[i][j] = (f32x4)0.0f; a2c[i][j] = (f32x4)0.0f; }

    #pragma unroll
    for (int ks = 0; ks < 4; ks++) {
        half8 a2h[2], a2l[2];
        #pragma unroll
        for (int mt2 = 0; mt2 < 2; mt2++) {
            const int row = wid * 32 + mt2 * 16 + l16;
            const int sw  = row & 7;
            const int cb  = ks * 8 + quad * 2;
            const uint4 q0 = *(const uint4*)(Hs + row * 128 + ((cb ^ sw) << 2));
            const uint4 q1 = *(const uint4*)(Hs + row * 128 + (((cb + 1) ^ sw) << 2));
            uint32_t u[8] = {q0.x, q0.y, q0.z, q0.w, q1.x, q1.y, q1.z, q1.w};
            U4H8 H, L;
            #pragma unroll
            for (int j = 0; j < 4; j++) {
                H.u[j] = (u[2 * j] & 0xffffu) | (u[2 * j + 1] << 16);
                L.u[j] = (u[2 * j] >> 16)     | (u[2 * j + 1] & 0xffff0000u);
            }
            a2h[mt2] = H.h; a2l[mt2] = L.h;
        }
        #pragma unroll
        for (int et = 0; et < 4; et++) {
            const int e = et * 16 + l16;
            const uint32_t* wp = W2Tp + (size_t)e * DIM + n0 + ks * 32 + quad * 8;
            const uint4 q0 = *(const uint4*)wp;
            const uint4 q1 = *(const uint4*)(wp + 4);
            uint32_t u[8] = {q0.x, q0.y, q0.z, q0.w, q1.x, q1.y, q1.z, q1.w};
            U4H8 H, L;
            #pragma unroll
            for (int j = 0; j < 4; j++) {
                H.u[j] = (u[2 * j] & 0xffffu) | (u[2 * j + 1] << 16);
                L.u[j] = (u[2 * j] >> 16)     | (u[2 * j + 1] & 0xffff0000u);
            }
            #pragma unroll
            for (int mt2 = 0; mt2 < 2; mt2++) {
                a2m[mt2][et] = MFMA_F16(a2h[mt2], H.h, a2m[mt2][et]);
                a2c[mt2][et] = MFMA_F16(a2h[mt2], L.h, a2c[mt2][et]);
                a2c[mt2][et] = MFMA_F16(a2l[mt2], H.h, a2c[mt2][et]);
            }
        }
    }

    #pragma unroll
    for (int mt2 = 0; mt2 < 2; mt2++)
        #pragma unroll
        for (int et = 0; et < 4; et++)
            #pragma unroll
            for (int r = 0; r < 4; r++) {
                const float lg = a2m[mt2][et][r] + a2c[mt2][et][r] * INV_LO_SCALE;
                const int rowm = m0 + wid * 32 + mt2 * 16 + quad * 4 + r;
                const int e = et * 16 + l16;
                atomicAdd(&Lp[(size_t)rowm * NEXP + e], lg);
            }
}

// ---------------------------------------------------------------------------
// routing + loss: last-block ticket pattern (loss folded into the router)
// ---------------------------------------------------------------------------
__global__ __launch_bounds__(256) void router_topk_v3(
    const float* __restrict__ Lp, const float* __restrict__ b2,
    float* __restrict__ out_rw, float* __restrict__ out_idx,
    float* __restrict__ gP, float* __restrict__ gI,
    float* __restrict__ out_loss, uint32_t* __restrict__ done)
{
    __shared__ float sP[NEXP];
    __shared__ float sI[NEXP];
    __shared__ uint32_t ticket;
    const int t = threadIdx.x;
    if (t < NEXP) { sP[t] = 0.f; sI[t] = 0.f; }
    __syncthreads();

    const int lane = t & 63;
    const int wv   = t >> 6;
    const float b2v = b2[lane];

    float accP = 0.f, accSel = 0.f;

    for (int i = 0; i < 16; i++) {
        const int tok = blockIdx.x * 64 + i * 4 + wv;
        float logit = Lp[(size_t)tok * NEXP + lane] + b2v;

        // full softmax over 64 experts (load-balance loss)
        float mx = logit;
        #pragma unroll
        for (int off = 32; off >= 1; off >>= 1) mx = fmaxf(mx, __shfl_xor(mx, off));
        float p = expf(logit - mx);
        float ps = p;
        #pragma unroll
        for (int off = 32; off >= 1; off >>= 1) ps += __shfl_xor(ps, off);
        accP += p / ps;

        // iterative top-8 argmax (min-index tiebreak)
        float cur = logit;
        float tv[TOPK]; int tix[TOPK];
        for (int k = 0; k < TOPK; k++) {
            float v = cur; int idx = lane;
            #pragma unroll
            for (int off = 32; off >= 1; off >>= 1) {
                float ov = __shfl_xor(v, off);
                int   oi = __shfl_xor(idx, off);
                if (ov > v || (ov == v && oi < idx)) { v = ov; idx = oi; }
            }
            tv[k] = v; tix[k] = idx;
            if (lane == idx) cur = -INFINITY;
        }

        float ev[TOPK], s = 0.f;
        #pragma unroll
        for (int k = 0; k < TOPK; k++) { ev[k] = expf(tv[k] - tv[0]); s += ev[k]; }
        float w = 0.f;
        #pragma unroll
        for (int k = 0; k < TOPK; k++)
            if (tix[k] == lane) { w = ev[k] / s; accSel += 1.f; }

        out_rw[(size_t)tok * NEXP + lane] = w;
        if (lane < TOPK) out_idx[(size_t)tok * TOPK + lane] = (float)tix[lane];
    }

    atomicAdd(&sP[lane], accP);
    atomicAdd(&sI[lane], accSel);
    __syncthreads();
    if (t < NEXP) { atomicAdd(&gP[t], sP[t]); atomicAdd(&gI[t], sI[t]); }

    // ---- last block computes the load-balance loss ----
    __threadfence();                         // release gP/gI contributions
    if (t == 0) ticket = atomicAdd(done, 1u);
    __syncthreads();
    if (ticket == (uint32_t)(gridDim.x - 1)) {
        __threadfence();                     // acquire
        if (t < NEXP) {
            const float inv = 1.0f / (float)N_TOK;
            float fI = atomicAdd(&gI[t], 0.0f);   // coherent read
            float fP = atomicAdd(&gP[t], 0.0f);
            float v = (fI * inv) * (fP * inv);
            #pragma unroll
            for (int off = 32; off >= 1; off >>= 1) v += __shfl_xor(v, off);
            if (t == 0) out_loss[0] = (float)NEXP * v;
        }
    }
}

extern "C" void kernel_launch(void* const* d_in, const int* in_sizes, int n_in,
                              void* d_out, int out_size, void* d_ws, size_t ws_size,
                              hipStream_t stream) {
    const float* x  = (const float*)d_in[0];
    const float* W1 = (const float*)d_in[1];
    const float* b1 = (const float*)d_in[2];
    const float* W2 = (const float*)d_in[3];
    const float* b2 = (const float*)d_in[4];

    float* out_rw   = (float*)d_out;
    float* out_idx  = out_rw + (size_t)N_TOK * NEXP;
    float* out_loss = out_idx + (size_t)N_TOK * TOPK;

    // ---- split-path ws layout (needs ~149 MiB) ----
    const size_t SZ_X   = (size_t)N_TOK * DIM * 2;      // 64 MiB per array
    const size_t SZ_W1  = (size_t)DIM * DIM * 2;        // 8 MiB per array
    const size_t OFF_XHI   = 0;
    const size_t OFF_XLO   = OFF_XHI + SZ_X;
    const size_t OFF_W1HI  = OFF_XLO + SZ_X;
    const size_t OFF_W1LO  = OFF_W1HI + SZ_W1;
    const size_t OFF_W2T   = OFF_W1LO + SZ_W1;
    const size_t OFF_LP    = OFF_W2T + (size_t)DIM * NEXP * 4;
    const size_t OFF_G     = OFF_LP + (size_t)N_TOK * NEXP * 4;
    const size_t needed_v2 = OFF_G + 2 * NEXP * 4 + 16;

    // ---- packed-path ws layout (~21 MiB) ----
    const size_t P_W1T = 0;
    const size_t P_W2T = (size_t)16 << 20;
    const size_t P_LP  = (size_t)17 << 20;
    const size_t P_G   = P_LP + (size_t)N_TOK * NEXP * 4;
    const size_t needed_p = P_G + 2 * NEXP * 4 + 16;

    if (ws_size >= needed_v2) {
        _Float16* xhi  = (_Float16*)((char*)d_ws + OFF_XHI);
        _Float16* xlo  = (_Float16*)((char*)d_ws + OFF_XLO);
        _Float16* w1hi = (_Float16*)((char*)d_ws + OFF_W1HI);
        _Float16* w1lo = (_Float16*)((char*)d_ws + OFF_W1LO);
        uint32_t* W2Tp = (uint32_t*)((char*)d_ws + OFF_W2T);
        float* Lp = (float*)((char*)d_ws + OFF_LP);
        float* gP = (float*)((char*)d_ws + OFF_G);
        float* gI = gP + NEXP;
        uint32_t* done = (uint32_t*)(gI + NEXP);

        (void)hipMemsetAsync((char*)d_ws + OFF_LP, 0,
                             (size_t)N_TOK * NEXP * 4 + 2 * NEXP * 4 + 16, stream);
        convert_all<<<CVT_XBLKS + CVT_W1BLKS + CVT_W2BLKS, 256, 0, stream>>>(
            x, W1, W2, xhi, xlo, w1hi, w1lo, W2Tp);
        gemm_fused_v2<<<(N_TOK / BM) * (DIM / BN), 256, 0, stream>>>(
            xhi, xlo, w1hi, w1lo, b1, W2Tp, Lp);
        router_topk_v3<<<N_TOK / 64, 256, 0, stream>>>(
            Lp, b2, out_rw, out_idx, gP, gI, out_loss, done);
    } else if (ws_size >= needed_p) {
        uint32_t* W1Tp = (uint32_t*)((char*)d_ws + P_W1T);
        uint32_t* W2Tp = (uint32_t*)((char*)d_ws + P_W2T);
        float* Lp = (float*)((char*)d_ws + P_LP);
        float* gP = (float*)((char*)d_ws + P_G);
        float* gI = gP + NEXP;
        uint32_t* done = (uint32_t*)(gI + NEXP);

        (void)hipMemsetAsync((char*)d_ws + P_LP, 0,
                             (size_t)N_TOK * NEXP * 4 + 2 * NEXP * 4 + 16, stream);
        convert_x_inplace<<<(N_TOK * DIM) / (256 * 4), 256, 0, stream>>>((float*)d_in[0]);
        convert_w1t_packed<<<dim3(DIM / 32, DIM / 32), 256, 0, stream>>>(W1, W1Tp);
        convert_w2t_packed<<<(NEXP * DIM) / 256, 256, 0, stream>>>(W2, W2Tp);
        gemm_fused<<<(N_TOK / BM) * (DIM / BN), 256, 0, stream>>>(
            (const uint32_t*)d_in[0], W1Tp, b1, W2Tp, Lp);
        router_topk_v3<<<N_TOK / 64, 256, 0, stream>>>(
            Lp, b2, out_rw, out_idx, gP, gI, out_loss, done);
    }
}

// Round 5
// 805.232 us; speedup vs baseline: 1.1904x; 1.1904x over previous
//
#include <hip/hip_runtime.h>
#include <math.h>
#include <stdint.h>

#define N_TOK 16384
#define DIM   2048
#define NEXP  64
#define TOPK  8

#define BM 128
#define BN 128
#define BKE 32          // k-elements per iteration

typedef _Float16 half8  __attribute__((ext_vector_type(8)));
typedef float    f32x4  __attribute__((ext_vector_type(4)));
typedef float    f32x16 __attribute__((ext_vector_type(16)));

#define GLOBAL_AS __attribute__((address_space(1)))
#define LDS_AS    __attribute__((address_space(3)))

#define LO_SCALE     4096.0f
#define INV_LO_SCALE (1.0f / 4096.0f)

// pack fp32 v -> u32: low16 = fp16(v), high16 = fp16((v - fp16(v)) * 4096)
__device__ inline uint32_t pack_split(float v) {
    _Float16 hi = (_Float16)v;
    float r = (v - (float)hi) * LO_SCALE;
    _Float16 lo = (_Float16)r;
    return (uint32_t)__builtin_bit_cast(uint16_t, hi) |
           ((uint32_t)__builtin_bit_cast(uint16_t, lo) << 16);
}

__device__ inline _Float16 split_hi(float v) { return (_Float16)v; }
__device__ inline _Float16 split_lo(float v) {
    _Float16 hi = (_Float16)v;
    return (_Float16)((v - (float)hi) * LO_SCALE);
}

union U4H8 { uint32_t u[4]; half8 h; };

// packed-u32 fragment loader (fallback path + epilogue W2 reads)
__device__ inline void load_frag(const uint32_t* base, int row, int quad,
                                 half8& hi, half8& lo) {
    const int sw = row & 7;
    const uint4 q0 = *(const uint4*)(base + row * 32 + (((quad * 2)     ^ sw) << 2));
    const uint4 q1 = *(const uint4*)(base + row * 32 + (((quad * 2 + 1) ^ sw) << 2));
    uint32_t u[8] = {q0.x, q0.y, q0.z, q0.w, q1.x, q1.y, q1.z, q1.w};
    U4H8 H, L;
    #pragma unroll
    for (int j = 0; j < 4; j++) {
        H.u[j] = (u[2 * j] & 0xffffu) | (u[2 * j + 1] << 16);
        L.u[j] = (u[2 * j] >> 16)     | (u[2 * j + 1] & 0xffff0000u);
    }
    hi = H.h; lo = L.h;
}

// split-array A/B fragment loader for the 32x32 main loop.
// LDS row = 64 halves = [32 hi | 32 lo] = 8 slots of 16B; logical chunk c
// lives at slot c ^ (row&7) ^ (((row>>3)&1)<<2).
// The row-bit-3 XOR term is needed for 32-row fragment reads: row stride is
// 128B (= bank period), so bank depends only on slot; without the extra
// term rows r and r+8 share a slot -> 8-way conflict. With it, only the
// free 2-way (r, r+16) aliasing remains.
__device__ inline int swz(int row) { return (row & 7) ^ (((row >> 3) & 1) << 2); }

__device__ inline void load_frag2(const _Float16* base, int row, int q,
                                  half8& hi, half8& lo) {
    const int sw = swz(row);
    hi = *(const half8*)(base + row * 64 + ((q       ^ sw) << 3));
    lo = *(const half8*)(base + row * 64 + (((q + 4) ^ sw) << 3));
}

// ---------------------------------------------------------------------------
// fused conversion kernel: block-range dispatch over {x-split, W1T-split, W2T}
// ---------------------------------------------------------------------------
#define CVT_XBLKS  ((N_TOK * DIM) / (256 * 8))            // 16384
#define CVT_W1BLKS ((DIM / 32) * (DIM / 32))              // 4096
#define CVT_W2BLKS ((NEXP * DIM) / 256)                   // 512

__global__ __launch_bounds__(256) void convert_all(
    const float* __restrict__ x, const float* __restrict__ W1,
    const float* __restrict__ W2,
    _Float16* __restrict__ xhi, _Float16* __restrict__ xlo,
    _Float16* __restrict__ w1hi, _Float16* __restrict__ w1lo,
    uint32_t* __restrict__ W2Tp)
{
    const int b = blockIdx.x;
    if (b < CVT_XBLKS) {
        size_t i = ((size_t)b * 256 + threadIdx.x) * 8;
        float4 v0 = *(const float4*)(x + i);
        float4 v1 = *(const float4*)(x + i + 4);
        const float vv[8] = {v0.x, v0.y, v0.z, v0.w, v1.x, v1.y, v1.z, v1.w};
        half8 h, l;
        #pragma unroll
        for (int j = 0; j < 8; j++) { h[j] = split_hi(vv[j]); l[j] = split_lo(vv[j]); }
        *(half8*)(xhi + i) = h;
        *(half8*)(xlo + i) = l;
    } else if (b < CVT_XBLKS + CVT_W1BLKS) {
        __shared__ float s[32][33];
        const int bb = b - CVT_XBLKS;
        const int n0 = (bb & 63) * 32, k0 = (bb >> 6) * 32;
        const int tr = threadIdx.x & 31, tc = threadIdx.x >> 5;   // 32 x 8
        #pragma unroll
        for (int r = 0; r < 4; r++) {
            int row = tc + r * 8;
            s[row][tr] = W1[(size_t)(k0 + row) * DIM + n0 + tr];
        }
        __syncthreads();
        #pragma unroll
        for (int r = 0; r < 4; r++) {
            int row = tc + r * 8;                                 // n-local
            float v = s[tr][row];
            w1hi[(size_t)(n0 + row) * DIM + k0 + tr] = split_hi(v);
            w1lo[(size_t)(n0 + row) * DIM + k0 + tr] = split_lo(v);
        }
    } else {
        const int i = (b - CVT_XBLKS - CVT_W1BLKS) * 256 + threadIdx.x;
        const int e = i >> 11, n = i & 2047;
        W2Tp[i] = pack_split(W2[(size_t)n * NEXP + e]);
    }
}

// in-place packed converter (mid-fallback path)
__global__ __launch_bounds__(256) void convert_x_inplace(float* __restrict__ x) {
    size_t i = ((size_t)blockIdx.x * 256 + threadIdx.x) * 4;
    float4 v = *(const float4*)(x + i);
    uint4 p;
    p.x = pack_split(v.x); p.y = pack_split(v.y);
    p.z = pack_split(v.z); p.w = pack_split(v.w);
    *(uint4*)(x + i) = p;
}

__global__ __launch_bounds__(256) void convert_w1t_packed(
    const float* __restrict__ W1, uint32_t* __restrict__ W1Tp)
{
    __shared__ float s[32][33];
    const int k0 = blockIdx.y * 32, n0 = blockIdx.x * 32;
    const int tr = threadIdx.x & 31, tc = threadIdx.x >> 5;
    #pragma unroll
    for (int r = 0; r < 4; r++) {
        int row = tc + r * 8;
        s[row][tr] = W1[(size_t)(k0 + row) * DIM + n0 + tr];
    }
    __syncthreads();
    #pragma unroll
    for (int r = 0; r < 4; r++) {
        int row = tc + r * 8;
        W1Tp[(size_t)(n0 + row) * DIM + k0 + tr] = pack_split(s[tr][row]);
    }
}

__global__ __launch_bounds__(256) void convert_w2t_packed(
    const float* __restrict__ W2, uint32_t* __restrict__ W2Tp) {
    int i = blockIdx.x * 256 + threadIdx.x;   // over 64*2048
    int e = i >> 11, n = i & 2047;
    W2Tp[i] = pack_split(W2[(size_t)n * NEXP + e]);
}

// ---------------------------------------------------------------------------
// fused GEMM v7: R2's proven counted-vmcnt double-buffer cadence (best: 435us)
// with the main loop moved to mfma_f32_32x32x16_f16.
// R4 post-mortem: B-from-global regressed 456->706 (scatter-shaped frag reads,
// exposed L2 latency) -> reverted. At 128^2 the pipes serialize (step 4088cy =
// MFMA 1862 + LDS-read 1536 + LDS-write 512); scheduling variants all pin at
// 45-46%. This round attacks the MFMA wall itself: 24 x 32x32x16 (8.45cy) =
// 203cy/wave vs 48 x 16x16x32 (4.85cy) = 233cy -> wall 1862->1624cy.
// Same LDS bytes, same acc VGPR count. C/D layout (HW-verified):
// col=lane&31, row=(reg&3)+8*(reg>>2)+4*(lane>>5).
// ---------------------------------------------------------------------------

#define MFMA_F16(a_, b_, c_)  __builtin_amdgcn_mfma_f32_16x16x32_f16(a_, b_, c_, 0, 0, 0)
#define MFMA32(a_, b_, c_)    __builtin_amdgcn_mfma_f32_32x32x16_f16(a_, b_, c_, 0, 0, 0)

// one K-step: read tile from (ASrc,BSrc), optionally stage next into (ASt,BSt).
// R2 cadence: stage(k+1) -> vmcnt(8) [tile k landed, k+1 stays in flight
// across the barrier, wait-distance = one full step] -> barrier -> reads ->
// MFMA (setprio) -> lgkmcnt(0) -> barrier [buf free for restage].
#define KSTEP(ASrc_, BSrc_, ASt_, BSt_, DOSTAGE_)                               \
    {                                                                           \
        if (DOSTAGE_) {                                                         \
            _Pragma("unroll")                                                   \
            for (int r = 0; r < 4; r++) {                                       \
                const int wslot = (r * 256 + wid * 64) << 2;                    \
                __builtin_amdgcn_global_load_lds(                               \
                    (const GLOBAL_AS uint32_t*)gA[r],                           \
                    (LDS_AS uint32_t*)((ASt_) + wslot), 16, 0, 0);              \
                __builtin_amdgcn_global_load_lds(                               \
                    (const GLOBAL_AS uint32_t*)gB[r],                           \
                    (LDS_AS uint32_t*)((BSt_) + wslot), 16, 0, 0);              \
                gA[r] += BKE; gB[r] += BKE;                                     \
            }                                                                   \
            asm volatile("s_waitcnt vmcnt(8)" ::: "memory");                    \
        } else {                                                                \
            asm volatile("s_waitcnt vmcnt(0)" ::: "memory");                    \
        }                                                                       \
        __builtin_amdgcn_s_barrier();                                           \
        half8 ah[2][2], al[2][2], bh[2][2], bl[2][2];                           \
        _Pragma("unroll")                                                       \
        for (int mi = 0; mi < 2; mi++)                                          \
            _Pragma("unroll")                                                   \
            for (int h = 0; h < 2; h++)                                         \
                load_frag2((const _Float16*)(ASrc_), wm + mi * 32 + r32,        \
                           h * 2 + kg, ah[mi][h], al[mi][h]);                   \
        _Pragma("unroll")                                                       \
        for (int ni = 0; ni < 2; ni++)                                          \
            _Pragma("unroll")                                                   \
            for (int h = 0; h < 2; h++)                                         \
                load_frag2((const _Float16*)(BSrc_), wn + ni * 32 + r32,        \
                           h * 2 + kg, bh[ni][h], bl[ni][h]);                   \
        __builtin_amdgcn_s_setprio(1);                                          \
        _Pragma("unroll")                                                       \
        for (int mi = 0; mi < 2; mi++)                                          \
            _Pragma("unroll")                                                   \
            for (int ni = 0; ni < 2; ni++)                                      \
                _Pragma("unroll")                                               \
                for (int h = 0; h < 2; h++) {                                   \
                    am[mi][ni] = MFMA32(ah[mi][h], bh[ni][h], am[mi][ni]);      \
                    ac[mi][ni] = MFMA32(ah[mi][h], bl[ni][h], ac[mi][ni]);      \
                    ac[mi][ni] = MFMA32(al[mi][h], bh[ni][h], ac[mi][ni]);      \
                }                                                               \
        __builtin_amdgcn_s_setprio(0);                                          \
        asm volatile("s_waitcnt lgkmcnt(0)" ::: "memory");                      \
        __builtin_amdgcn_s_barrier();                                           \
    }

__global__ __launch_bounds__(256, 2) void gemm_fused_v2(
    const _Float16* __restrict__ xhi, const _Float16* __restrict__ xlo,
    const _Float16* __restrict__ w1hi, const _Float16* __restrict__ w1lo,
    const float* __restrict__ b1, const uint32_t* __restrict__ W2Tp,
    float* __restrict__ Lp)
{
    __shared__ uint32_t smem[16384];          // 64 KB
    uint32_t* A0 = smem;                      // [128][64] halves, 16 KB
    uint32_t* B0 = smem + 4096;
    uint32_t* A1 = smem + 8192;               // double-buffer partners
    uint32_t* B1 = smem + 12288;

    const int t    = threadIdx.x;
    const int wid  = t >> 6;
    const int lane = t & 63;
    const int quad = lane >> 4;               // GEMM2 (16x16) indices
    const int l16  = lane & 15;
    const int r32  = lane & 31;               // GEMM1 (32x32) indices
    const int kg   = lane >> 5;

    // block swizzle: groups of 8 m-blocks share one n-block (W1T slice L2 reuse)
    const int lin = blockIdx.x;               // 2048 blocks
    const int grp = lin >> 7;
    const int rem = lin & 127;
    const int m0 = (grp * 8 + (rem & 7)) * BM;
    const int n0 = (rem >> 3) * BN;

    // staging source pointers; LDS slot s of row r holds logical chunk
    // c = s ^ swz(r); c<4 -> hi array chunk c, else lo array chunk c-4.
    const _Float16* gA[4];
    const _Float16* gB[4];
    #pragma unroll
    for (int r = 0; r < 4; r++) {
        int s_lin = r * 256 + t;
        int row = s_lin >> 3;
        int c   = (s_lin & 7) ^ swz(row);
        gA[r] = (c < 4) ? xhi  + (size_t)(m0 + row) * DIM + c * 8
                        : xlo  + (size_t)(m0 + row) * DIM + (c - 4) * 8;
        gB[r] = (c < 4) ? w1hi + (size_t)(n0 + row) * DIM + c * 8
                        : w1lo + (size_t)(n0 + row) * DIM + (c - 4) * 8;
    }

    f32x16 am[2][2], ac[2][2];
    #pragma unroll
    for (int i = 0; i < 2; i++)
        #pragma unroll
        for (int j = 0; j < 2; j++) { am[i][j] = (f32x16)0.0f; ac[i][j] = (f32x16)0.0f; }

    const int wm = (wid & 1) * 64;
    const int wn = (wid >> 1) * 64;

    // prologue: stage tile 0 into buf0 (8 loads in flight)
    #pragma unroll
    for (int r = 0; r < 4; r++) {
        const int wslot = (r * 256 + wid * 64) << 2;
        __builtin_amdgcn_global_load_lds((const GLOBAL_AS uint32_t*)gA[r],
                                         (LDS_AS uint32_t*)(A0 + wslot), 16, 0, 0);
        __builtin_amdgcn_global_load_lds((const GLOBAL_AS uint32_t*)gB[r],
                                         (LDS_AS uint32_t*)(B0 + wslot), 16, 0, 0);
        gA[r] += BKE; gB[r] += BKE;
    }

    // 64 K-steps as 32 pairs; buffers alternate with static addresses.
    for (int kp = 0; kp < 32; kp++) {
        KSTEP(A0, B0, A1, B1, true);        // read buf0, stage tile(2kp+1)
        KSTEP(A1, B1, A0, B0, kp != 31);    // read buf1, stage tile(2kp+2)
    }

    // ---- epilogue: bias + exact GELU, pack h into swizzled LDS [128][128] ----
    // 32x32 C layout: col = lane&31, row = (reg&3) + 8*(reg>>2) + 4*(lane>>5)
    uint32_t* Hs = smem;
    #pragma unroll
    for (int mi = 0; mi < 2; mi++)
        #pragma unroll
        for (int ni = 0; ni < 2; ni++) {
            const int coln = wn + ni * 32 + r32;
            const float b1v = b1[n0 + coln];
            #pragma unroll
            for (int r = 0; r < 16; r++) {
                float h = am[mi][ni][r] + ac[mi][ni][r] * INV_LO_SCALE + b1v;
                h = 0.5f * h * (1.0f + erff(h * 0.70710678118654752440f));
                const int rowm = wm + mi * 32 + (r & 3) + 8 * (r >> 2) + 4 * kg;
                const int word = rowm * 128 + ((((coln >> 2) ^ (rowm & 7)) << 2) | (coln & 3));
                Hs[word] = pack_split(h);
            }
        }
    __syncthreads();

    // ---- GEMM2: logits[128 x 64] = h[128 x 128] @ W2T' (4 K=32 steps) ----
    f32x4 a2m[2][4], a2c[2][4];
    #pragma unroll
    for (int i = 0; i < 2; i++)
        #pragma unroll
        for (int j = 0; j < 4; j++) { a2m[i][j] = (f32x4)0.0f; a2c[i][j] = (f32x4)0.0f; }

    #pragma unroll
    for (int ks = 0; ks < 4; ks++) {
        half8 a2h[2], a2l[2];
        #pragma unroll
        for (int mt2 = 0; mt2 < 2; mt2++) {
            const int row = wid * 32 + mt2 * 16 + l16;
            const int sw  = row & 7;
            const int cb  = ks * 8 + quad * 2;           // k = ks*32 + quad*8 + j
            const uint4 q0 = *(const uint4*)(Hs + row * 128 + ((cb ^ sw) << 2));
            const uint4 q1 = *(const uint4*)(Hs + row * 128 + (((cb + 1) ^ sw) << 2));
            uint32_t u[8] = {q0.x, q0.y, q0.z, q0.w, q1.x, q1.y, q1.z, q1.w};
            U4H8 H, L;
            #pragma unroll
            for (int j = 0; j < 4; j++) {
                H.u[j] = (u[2 * j] & 0xffffu) | (u[2 * j + 1] << 16);
                L.u[j] = (u[2 * j] >> 16)     | (u[2 * j + 1] & 0xffff0000u);
            }
            a2h[mt2] = H.h; a2l[mt2] = L.h;
        }
        #pragma unroll
        for (int et = 0; et < 4; et++) {
            const int e = et * 16 + l16;
            const uint32_t* wp = W2Tp + (size_t)e * DIM + n0 + ks * 32 + quad * 8;
            const uint4 q0 = *(const uint4*)wp;
            const uint4 q1 = *(const uint4*)(wp + 4);
            uint32_t u[8] = {q0.x, q0.y, q0.z, q0.w, q1.x, q1.y, q1.z, q1.w};
            U4H8 H, L;
            #pragma unroll
            for (int j = 0; j < 4; j++) {
                H.u[j] = (u[2 * j] & 0xffffu) | (u[2 * j + 1] << 16);
                L.u[j] = (u[2 * j] >> 16)     | (u[2 * j + 1] & 0xffff0000u);
            }
            #pragma unroll
            for (int mt2 = 0; mt2 < 2; mt2++) {
                a2m[mt2][et] = MFMA_F16(a2h[mt2], H.h, a2m[mt2][et]);
                a2c[mt2][et] = MFMA_F16(a2h[mt2], L.h, a2c[mt2][et]);
                a2c[mt2][et] = MFMA_F16(a2l[mt2], H.h, a2c[mt2][et]);
            }
        }
    }

    #pragma unroll
    for (int mt2 = 0; mt2 < 2; mt2++)
        #pragma unroll
        for (int et = 0; et < 4; et++)
            #pragma unroll
            for (int r = 0; r < 4; r++) {
                const float lg = a2m[mt2][et][r] + a2c[mt2][et][r] * INV_LO_SCALE;
                const int rowm = m0 + wid * 32 + mt2 * 16 + quad * 4 + r;
                const int e = et * 16 + l16;
                atomicAdd(&Lp[(size_t)rowm * NEXP + e], lg);
            }
}

// ---------------------------------------------------------------------------
// packed-u32 fused GEMM (mid fallback, needs only ~21 MB ws)
// ---------------------------------------------------------------------------
__global__ __launch_bounds__(256, 2) void gemm_fused(
    const uint32_t* __restrict__ xp, const uint32_t* __restrict__ W1Tp,
    const float* __restrict__ b1, const uint32_t* __restrict__ W2Tp,
    float* __restrict__ Lp)
{
    __shared__ uint32_t smem[16384];
    uint32_t* Ap = smem;
    uint32_t* Bp = smem + 4096;

    const int t    = threadIdx.x;
    const int wid  = t >> 6;
    const int lane = t & 63;
    const int quad = lane >> 4;
    const int l16  = lane & 15;

    const int lin = blockIdx.x;
    const int grp = lin >> 7;
    const int rem = lin & 127;
    const int m0 = (grp * 8 + (rem & 7)) * BM;
    const int n0 = (rem >> 3) * BN;

    const uint32_t* gA[4];
    const uint32_t* gB[4];
    #pragma unroll
    for (int r = 0; r < 4; r++) {
        int s = r * 256 + t;
        int row = s >> 3;
        int c   = s & 7;
        int co  = (c ^ (row & 7)) << 2;
        gA[r] = xp   + (size_t)(m0 + row) * DIM + co;
        gB[r] = W1Tp + (size_t)(n0 + row) * DIM + co;
    }

    f32x4 am[4][4], ac[4][4];
    #pragma unroll
    for (int i = 0; i < 4; i++)
        #pragma unroll
        for (int j = 0; j < 4; j++) { am[i][j] = (f32x4)0.0f; ac[i][j] = (f32x4)0.0f; }

    const int wm = (wid & 1) * 64;
    const int wn = (wid >> 1) * 64;

    for (int k0 = 0; k0 < DIM; k0 += BKE) {
        #pragma unroll
        for (int r = 0; r < 4; r++) {
            const int wslot = (r * 256 + wid * 64) << 2;
            __builtin_amdgcn_global_load_lds((const GLOBAL_AS uint32_t*)gA[r],
                                             (LDS_AS uint32_t*)(Ap + wslot), 16, 0, 0);
            __builtin_amdgcn_global_load_lds((const GLOBAL_AS uint32_t*)gB[r],
                                             (LDS_AS uint32_t*)(Bp + wslot), 16, 0, 0);
            gA[r] += BKE; gB[r] += BKE;
        }
        __syncthreads();

        half8 ah[4], al[4], bh[4], bl[4];
        #pragma unroll
        for (int mt = 0; mt < 4; mt++)
            load_frag(Ap, wm + mt * 16 + l16, quad, ah[mt], al[mt]);
        #pragma unroll
        for (int nt = 0; nt < 4; nt++)
            load_frag(Bp, wn + nt * 16 + l16, quad, bh[nt], bl[nt]);

        #pragma unroll
        for (int mt = 0; mt < 4; mt++)
            #pragma unroll
            for (int nt = 0; nt < 4; nt++) {
                am[mt][nt] = MFMA_F16(ah[mt], bh[nt], am[mt][nt]);
                ac[mt][nt] = MFMA_F16(ah[mt], bl[nt], ac[mt][nt]);
                ac[mt][nt] = MFMA_F16(al[mt], bh[nt], ac[mt][nt]);
            }
        __syncthreads();
    }

    uint32_t* Hs = smem;
    #pragma unroll
    for (int mt = 0; mt < 4; mt++)
        #pragma unroll
        for (int nt = 0; nt < 4; nt++) {
            const int coln = wn + nt * 16 + l16;
            const float b1v = b1[n0 + coln];
            #pragma unroll
            for (int r = 0; r < 4; r++) {
                float h = am[mt][nt][r] + ac[mt][nt][r] * INV_LO_SCALE + b1v;
                h = 0.5f * h * (1.0f + erff(h * 0.70710678118654752440f));
                const int rowm = wm + mt * 16 + quad * 4 + r;
                const int word = rowm * 128 + ((((coln >> 2) ^ (rowm & 7)) << 2) | (coln & 3));
                Hs[word] = pack_split(h);
            }
        }
    __syncthreads();

    f32x4 a2m[2][4], a2c[2][4];
    #pragma unroll
    for (int i = 0; i < 2; i++)
        #pragma unroll
        for (int j = 0; j < 4; j++) { a2m[i][j] = (f32x4)0.0f; a2c[i][j] = (f32x4)0.0f; }

    #pragma unroll
    for (int ks = 0; ks < 4; ks++) {
        half8 a2h[2], a2l[2];
        #pragma unroll
        for (int mt2 = 0; mt2 < 2; mt2++) {
            const int row = wid * 32 + mt2 * 16 + l16;
            const int sw  = row & 7;
            const int cb  = ks * 8 + quad * 2;
            const uint4 q0 = *(const uint4*)(Hs + row * 128 + ((cb ^ sw) << 2));
            const uint4 q1 = *(const uint4*)(Hs + row * 128 + (((cb + 1) ^ sw) << 2));
            uint32_t u[8] = {q0.x, q0.y, q0.z, q0.w, q1.x, q1.y, q1.z, q1.w};
            U4H8 H, L;
            #pragma unroll
            for (int j = 0; j < 4; j++) {
                H.u[j] = (u[2 * j] & 0xffffu) | (u[2 * j + 1] << 16);
                L.u[j] = (u[2 * j] >> 16)     | (u[2 * j + 1] & 0xffff0000u);
            }
            a2h[mt2] = H.h; a2l[mt2] = L.h;
        }
        #pragma unroll
        for (int et = 0; et < 4; et++) {
            const int e = et * 16 + l16;
            const uint32_t* wp = W2Tp + (size_t)e * DIM + n0 + ks * 32 + quad * 8;
            const uint4 q0 = *(const uint4*)wp;
            const uint4 q1 = *(const uint4*)(wp + 4);
            uint32_t u[8] = {q0.x, q0.y, q0.z, q0.w, q1.x, q1.y, q1.z, q1.w};
            U4H8 H, L;
            #pragma unroll
            for (int j = 0; j < 4; j++) {
                H.u[j] = (u[2 * j] & 0xffffu) | (u[2 * j + 1] << 16);
                L.u[j] = (u[2 * j] >> 16)     | (u[2 * j + 1] & 0xffff0000u);
            }
            #pragma unroll
            for (int mt2 = 0; mt2 < 2; mt2++) {
                a2m[mt2][et] = MFMA_F16(a2h[mt2], H.h, a2m[mt2][et]);
                a2c[mt2][et] = MFMA_F16(a2h[mt2], L.h, a2c[mt2][et]);
                a2c[mt2][et] = MFMA_F16(a2l[mt2], H.h, a2c[mt2][et]);
            }
        }
    }

    #pragma unroll
    for (int mt2 = 0; mt2 < 2; mt2++)
        #pragma unroll
        for (int et = 0; et < 4; et++)
            #pragma unroll
            for (int r = 0; r < 4; r++) {
                const float lg = a2m[mt2][et][r] + a2c[mt2][et][r] * INV_LO_SCALE;
                const int rowm = m0 + wid * 32 + mt2 * 16 + quad * 4 + r;
                const int e = et * 16 + l16;
                atomicAdd(&Lp[(size_t)rowm * NEXP + e], lg);
            }
}

// ---------------------------------------------------------------------------
// routing + loss: last-block ticket pattern (loss folded into the router)
// ---------------------------------------------------------------------------
__global__ __launch_bounds__(256) void router_topk_v3(
    const float* __restrict__ Lp, const float* __restrict__ b2,
    float* __restrict__ out_rw, float* __restrict__ out_idx,
    float* __restrict__ gP, float* __restrict__ gI,
    float* __restrict__ out_loss, uint32_t* __restrict__ done)
{
    __shared__ float sP[NEXP];
    __shared__ float sI[NEXP];
    __shared__ uint32_t ticket;
    const int t = threadIdx.x;
    if (t < NEXP) { sP[t] = 0.f; sI[t] = 0.f; }
    __syncthreads();

    const int lane = t & 63;
    const int wv   = t >> 6;
    const float b2v = b2[lane];

    float accP = 0.f, accSel = 0.f;

    for (int i = 0; i < 16; i++) {
        const int tok = blockIdx.x * 64 + i * 4 + wv;
        float logit = Lp[(size_t)tok * NEXP + lane] + b2v;

        // full softmax over 64 experts (load-balance loss)
        float mx = logit;
        #pragma unroll
        for (int off = 32; off >= 1; off >>= 1) mx = fmaxf(mx, __shfl_xor(mx, off));
        float p = expf(logit - mx);
        float ps = p;
        #pragma unroll
        for (int off = 32; off >= 1; off >>= 1) ps += __shfl_xor(ps, off);
        accP += p / ps;

        // iterative top-8 argmax (min-index tiebreak)
        float cur = logit;
        float tv[TOPK]; int tix[TOPK];
        for (int k = 0; k < TOPK; k++) {
            float v = cur; int idx = lane;
            #pragma unroll
            for (int off = 32; off >= 1; off >>= 1) {
                float ov = __shfl_xor(v, off);
                int   oi = __shfl_xor(idx, off);
                if (ov > v || (ov == v && oi < idx)) { v = ov; idx = oi; }
            }
            tv[k] = v; tix[k] = idx;
            if (lane == idx) cur = -INFINITY;
        }

        float ev[TOPK], s = 0.f;
        #pragma unroll
        for (int k = 0; k < TOPK; k++) { ev[k] = expf(tv[k] - tv[0]); s += ev[k]; }
        float w = 0.f;
        #pragma unroll
        for (int k = 0; k < TOPK; k++)
            if (tix[k] == lane) { w = ev[k] / s; accSel += 1.f; }

        out_rw[(size_t)tok * NEXP + lane] = w;
        if (lane < TOPK) out_idx[(size_t)tok * TOPK + lane] = (float)tix[lane];
    }

    atomicAdd(&sP[lane], accP);
    atomicAdd(&sI[lane], accSel);
    __syncthreads();
    if (t < NEXP) { atomicAdd(&gP[t], sP[t]); atomicAdd(&gI[t], sI[t]); }

    // ---- last block computes the load-balance loss ----
    __threadfence();                         // release gP/gI contributions
    if (t == 0) ticket = atomicAdd(done, 1u);
    __syncthreads();
    if (ticket == (uint32_t)(gridDim.x - 1)) {
        __threadfence();                     // acquire
        if (t < NEXP) {
            const float inv = 1.0f / (float)N_TOK;
            float fI = atomicAdd(&gI[t], 0.0f);   // coherent read
            float fP = atomicAdd(&gP[t], 0.0f);
            float v = (fI * inv) * (fP * inv);
            #pragma unroll
            for (int off = 32; off >= 1; off >>= 1) v += __shfl_xor(v, off);
            if (t == 0) out_loss[0] = (float)NEXP * v;
        }
    }
}

extern "C" void kernel_launch(void* const* d_in, const int* in_sizes, int n_in,
                              void* d_out, int out_size, void* d_ws, size_t ws_size,
                              hipStream_t stream) {
    const float* x  = (const float*)d_in[0];
    const float* W1 = (const float*)d_in[1];
    const float* b1 = (const float*)d_in[2];
    const float* W2 = (const float*)d_in[3];
    const float* b2 = (const float*)d_in[4];

    float* out_rw   = (float*)d_out;
    float* out_idx  = out_rw + (size_t)N_TOK * NEXP;
    float* out_loss = out_idx + (size_t)N_TOK * TOPK;

    // ---- split-path ws layout (needs ~149 MiB) ----
    const size_t SZ_X   = (size_t)N_TOK * DIM * 2;      // 64 MiB per array
    const size_t SZ_W1  = (size_t)DIM * DIM * 2;        // 8 MiB per array
    const size_t OFF_XHI   = 0;
    const size_t OFF_XLO   = OFF_XHI + SZ_X;
    const size_t OFF_W1HI  = OFF_XLO + SZ_X;
    const size_t OFF_W1LO  = OFF_W1HI + SZ_W1;
    const size_t OFF_W2T   = OFF_W1LO + SZ_W1;
    const size_t OFF_LP    = OFF_W2T + (size_t)DIM * NEXP * 4;
    const size_t OFF_G     = OFF_LP + (size_t)N_TOK * NEXP * 4;
    const size_t needed_v2 = OFF_G + 2 * NEXP * 4 + 16;

    // ---- packed-path ws layout (~21 MiB) ----
    const size_t P_W1T = 0;
    const size_t P_W2T = (size_t)16 << 20;
    const size_t P_LP  = (size_t)17 << 20;
    const size_t P_G   = P_LP + (size_t)N_TOK * NEXP * 4;
    const size_t needed_p = P_G + 2 * NEXP * 4 + 16;

    if (ws_size >= needed_v2) {
        _Float16* xhi  = (_Float16*)((char*)d_ws + OFF_XHI);
        _Float16* xlo  = (_Float16*)((char*)d_ws + OFF_XLO);
        _Float16* w1hi = (_Float16*)((char*)d_ws + OFF_W1HI);
        _Float16* w1lo = (_Float16*)((char*)d_ws + OFF_W1LO);
        uint32_t* W2Tp = (uint32_t*)((char*)d_ws + OFF_W2T);
        float* Lp = (float*)((char*)d_ws + OFF_LP);
        float* gP = (float*)((char*)d_ws + OFF_G);
        float* gI = gP + NEXP;
        uint32_t* done = (uint32_t*)(gI + NEXP);

        (void)hipMemsetAsync((char*)d_ws + OFF_LP, 0,
                             (size_t)N_TOK * NEXP * 4 + 2 * NEXP * 4 + 16, stream);
        convert_all<<<CVT_XBLKS + CVT_W1BLKS + CVT_W2BLKS, 256, 0, stream>>>(
            x, W1, W2, xhi, xlo, w1hi, w1lo, W2Tp);
        gemm_fused_v2<<<(N_TOK / BM) * (DIM / BN), 256, 0, stream>>>(
            xhi, xlo, w1hi, w1lo, b1, W2Tp, Lp);
        router_topk_v3<<<N_TOK / 64, 256, 0, stream>>>(
            Lp, b2, out_rw, out_idx, gP, gI, out_loss, done);
    } else if (ws_size >= needed_p) {
        uint32_t* W1Tp = (uint32_t*)((char*)d_ws + P_W1T);
        uint32_t* W2Tp = (uint32_t*)((char*)d_ws + P_W2T);
        float* Lp = (float*)((char*)d_ws + P_LP);
        float* gP = (float*)((char*)d_ws + P_G);
        float* gI = gP + NEXP;
        uint32_t* done = (uint32_t*)(gI + NEXP);

        (void)hipMemsetAsync((char*)d_ws + P_LP, 0,
                             (size_t)N_TOK * NEXP * 4 + 2 * NEXP * 4 + 16, stream);
        convert_x_inplace<<<(N_TOK * DIM) / (256 * 4), 256, 0, stream>>>((float*)d_in[0]);
        convert_w1t_packed<<<dim3(DIM / 32, DIM / 32), 256, 0, stream>>>(W1, W1Tp);
        convert_w2t_packed<<<(NEXP * DIM) / 256, 256, 0, stream>>>(W2, W2Tp);
        gemm_fused<<<(N_TOK / BM) * (DIM / BN), 256, 0, stream>>>(
            (const uint32_t*)d_in[0], W1Tp, b1, W2Tp, Lp);
        router_topk_v3<<<N_TOK / 64, 256, 0, stream>>>(
            Lp, b2, out_rw, out_idx, gP, gI, out_loss, done);
    }
}

// Round 6
// 742.702 us; speedup vs baseline: 1.2906x; 1.0842x over previous
//
#include <hip/hip_runtime.h>
#include <math.h>
#include <stdint.h>

#define N_TOK 16384
#define DIM   2048
#define NEXP  64
#define TOPK  8

#define BM 128
#define BN 128
#define BKE 32          // k-elements per iteration

typedef _Float16 half8  __attribute__((ext_vector_type(8)));
typedef float    f32x4  __attribute__((ext_vector_type(4)));

#define GLOBAL_AS __attribute__((address_space(1)))
#define LDS_AS    __attribute__((address_space(3)))

#define LO_SCALE     4096.0f
#define INV_LO_SCALE (1.0f / 4096.0f)

// pack fp32 v -> u32: low16 = fp16(v), high16 = fp16((v - fp16(v)) * 4096)
__device__ inline uint32_t pack_split(float v) {
    _Float16 hi = (_Float16)v;
    float r = (v - (float)hi) * LO_SCALE;
    _Float16 lo = (_Float16)r;
    return (uint32_t)__builtin_bit_cast(uint16_t, hi) |
           ((uint32_t)__builtin_bit_cast(uint16_t, lo) << 16);
}

__device__ inline _Float16 split_hi(float v) { return (_Float16)v; }
__device__ inline _Float16 split_lo(float v) {
    _Float16 hi = (_Float16)v;
    return (_Float16)((v - (float)hi) * LO_SCALE);
}

union U4H8 { uint32_t u[4]; half8 h; };

// packed-u32 fragment loader (fallback path + epilogue W2 reads)
__device__ inline void load_frag(const uint32_t* base, int row, int quad,
                                 half8& hi, half8& lo) {
    const int sw = row & 7;
    const uint4 q0 = *(const uint4*)(base + row * 32 + (((quad * 2)     ^ sw) << 2));
    const uint4 q1 = *(const uint4*)(base + row * 32 + (((quad * 2 + 1) ^ sw) << 2));
    uint32_t u[8] = {q0.x, q0.y, q0.z, q0.w, q1.x, q1.y, q1.z, q1.w};
    U4H8 H, L;
    #pragma unroll
    for (int j = 0; j < 4; j++) {
        H.u[j] = (u[2 * j] & 0xffffu) | (u[2 * j + 1] << 16);
        L.u[j] = (u[2 * j] >> 16)     | (u[2 * j + 1] & 0xffff0000u);
    }
    hi = H.h; lo = L.h;
}

// clean split-array fragment loader (R2-proven, 16-row frag reads):
// LDS row = 64 halves = [32 hi | 32 lo] = 8 slots of 16B; logical chunk c
// lives at slot c ^ (row&7). 16 rows x 4 quads -> 64 distinct slots,
// 2-way bank aliasing only (free, m136).
__device__ inline void load_frag2(const _Float16* base, int row, int quad,
                                  half8& hi, half8& lo) {
    const int sw = row & 7;
    hi = *(const half8*)(base + row * 64 + ((quad       ^ sw) << 3));
    lo = *(const half8*)(base + row * 64 + (((quad + 4) ^ sw) << 3));
}

// ---------------------------------------------------------------------------
// fused conversion kernel: block-range dispatch over {x-split, W1T-split, W2T}
// ---------------------------------------------------------------------------
#define CVT_XBLKS  ((N_TOK * DIM) / (256 * 8))            // 16384
#define CVT_W1BLKS ((DIM / 32) * (DIM / 32))              // 4096
#define CVT_W2BLKS ((NEXP * DIM) / 256)                   // 512

__global__ __launch_bounds__(256) void convert_all(
    const float* __restrict__ x, const float* __restrict__ W1,
    const float* __restrict__ W2,
    _Float16* __restrict__ xhi, _Float16* __restrict__ xlo,
    _Float16* __restrict__ w1hi, _Float16* __restrict__ w1lo,
    uint32_t* __restrict__ W2Tp)
{
    const int b = blockIdx.x;
    if (b < CVT_XBLKS) {
        size_t i = ((size_t)b * 256 + threadIdx.x) * 8;
        float4 v0 = *(const float4*)(x + i);
        float4 v1 = *(const float4*)(x + i + 4);
        const float vv[8] = {v0.x, v0.y, v0.z, v0.w, v1.x, v1.y, v1.z, v1.w};
        half8 h, l;
        #pragma unroll
        for (int j = 0; j < 8; j++) { h[j] = split_hi(vv[j]); l[j] = split_lo(vv[j]); }
        *(half8*)(xhi + i) = h;
        *(half8*)(xlo + i) = l;
    } else if (b < CVT_XBLKS + CVT_W1BLKS) {
        __shared__ float s[32][33];
        const int bb = b - CVT_XBLKS;
        const int n0 = (bb & 63) * 32, k0 = (bb >> 6) * 32;
        const int tr = threadIdx.x & 31, tc = threadIdx.x >> 5;   // 32 x 8
        #pragma unroll
        for (int r = 0; r < 4; r++) {
            int row = tc + r * 8;
            s[row][tr] = W1[(size_t)(k0 + row) * DIM + n0 + tr];
        }
        __syncthreads();
        #pragma unroll
        for (int r = 0; r < 4; r++) {
            int row = tc + r * 8;                                 // n-local
            float v = s[tr][row];
            w1hi[(size_t)(n0 + row) * DIM + k0 + tr] = split_hi(v);
            w1lo[(size_t)(n0 + row) * DIM + k0 + tr] = split_lo(v);
        }
    } else {
        const int i = (b - CVT_XBLKS - CVT_W1BLKS) * 256 + threadIdx.x;
        const int e = i >> 11, n = i & 2047;
        W2Tp[i] = pack_split(W2[(size_t)n * NEXP + e]);
    }
}

// in-place packed converter (mid-fallback path)
__global__ __launch_bounds__(256) void convert_x_inplace(float* __restrict__ x) {
    size_t i = ((size_t)blockIdx.x * 256 + threadIdx.x) * 4;
    float4 v = *(const float4*)(x + i);
    uint4 p;
    p.x = pack_split(v.x); p.y = pack_split(v.y);
    p.z = pack_split(v.z); p.w = pack_split(v.w);
    *(uint4*)(x + i) = p;
}

__global__ __launch_bounds__(256) void convert_w1t_packed(
    const float* __restrict__ W1, uint32_t* __restrict__ W1Tp)
{
    __shared__ float s[32][33];
    const int k0 = blockIdx.y * 32, n0 = blockIdx.x * 32;
    const int tr = threadIdx.x & 31, tc = threadIdx.x >> 5;
    #pragma unroll
    for (int r = 0; r < 4; r++) {
        int row = tc + r * 8;
        s[row][tr] = W1[(size_t)(k0 + row) * DIM + n0 + tr];
    }
    __syncthreads();
    #pragma unroll
    for (int r = 0; r < 4; r++) {
        int row = tc + r * 8;
        W1Tp[(size_t)(n0 + row) * DIM + k0 + tr] = pack_split(s[tr][row]);
    }
}

__global__ __launch_bounds__(256) void convert_w2t_packed(
    const float* __restrict__ W2, uint32_t* __restrict__ W2Tp) {
    int i = blockIdx.x * 256 + threadIdx.x;   // over 64*2048
    int e = i >> 11, n = i & 2047;
    W2Tp[i] = pack_split(W2[(size_t)n * NEXP + e]);
}

// ---------------------------------------------------------------------------
// fused GEMM v8: exact R2 structure (best measured: 435us, MfmaUtil 46%)
// + cross-block anti-phase desync.
// R5 post-mortem: 32x32 MFMA shape -> 34M bank conflicts (65x), reverted.
// Standing model: per CU per K-step = MFMA 1862cy + LDS-read 1536cy +
// LDS-write 512cy ~= measured 4086cy: the two co-resident blocks are
// PHASE-LOCKED (launched together, identical barrier cadence) so the
// per-CU MFMA and LDS pipes serialize instead of overlapping. Fix: offset
// one of the two CU-mates by half a step (s_sleep 31 ~ 1984cy) before the
// main loop; mates then run anti-phase (one MFMAs while the other reads
// LDS). Accumulation semantics unchanged; worst case = R2 + 2us.
// ---------------------------------------------------------------------------

#define MFMA_F16(a_, b_, c_)  __builtin_amdgcn_mfma_f32_16x16x32_f16(a_, b_, c_, 0, 0, 0)

// one K-step: read tile from (ASrc,BSrc), optionally stage next into (ASt,BSt).
// R2 cadence: stage(k+1) -> vmcnt(8) [tile k landed; k+1's 8 loads stay in
// flight ACROSS the barrier, wait-distance = one full step] -> barrier ->
// frag reads -> MFMA (setprio) -> lgkmcnt(0) -> barrier [buf restage-safe].
#define KSTEP(ASrc_, BSrc_, ASt_, BSt_, DOSTAGE_)                               \
    {                                                                           \
        if (DOSTAGE_) {                                                         \
            _Pragma("unroll")                                                   \
            for (int r = 0; r < 4; r++) {                                       \
                const int wslot = (r * 256 + wid * 64) << 2;                    \
                __builtin_amdgcn_global_load_lds(                               \
                    (const GLOBAL_AS uint32_t*)gA[r],                           \
                    (LDS_AS uint32_t*)((ASt_) + wslot), 16, 0, 0);              \
                __builtin_amdgcn_global_load_lds(                               \
                    (const GLOBAL_AS uint32_t*)gB[r],                           \
                    (LDS_AS uint32_t*)((BSt_) + wslot), 16, 0, 0);              \
                gA[r] += BKE; gB[r] += BKE;                                     \
            }                                                                   \
            asm volatile("s_waitcnt vmcnt(8)" ::: "memory");                    \
        } else {                                                                \
            asm volatile("s_waitcnt vmcnt(0)" ::: "memory");                    \
        }                                                                       \
        __builtin_amdgcn_s_barrier();                                           \
        half8 ah[4], al[4], bh[4], bl[4];                                       \
        _Pragma("unroll")                                                       \
        for (int mt = 0; mt < 4; mt++)                                          \
            load_frag2((const _Float16*)(ASrc_), wm + mt * 16 + l16, quad,      \
                       ah[mt], al[mt]);                                         \
        _Pragma("unroll")                                                       \
        for (int nt = 0; nt < 4; nt++)                                          \
            load_frag2((const _Float16*)(BSrc_), wn + nt * 16 + l16, quad,      \
                       bh[nt], bl[nt]);                                         \
        __builtin_amdgcn_s_setprio(1);                                          \
        _Pragma("unroll")                                                       \
        for (int mt = 0; mt < 4; mt++)                                          \
            _Pragma("unroll")                                                   \
            for (int nt = 0; nt < 4; nt++) {                                    \
                am[mt][nt] = MFMA_F16(ah[mt], bh[nt], am[mt][nt]);              \
                ac[mt][nt] = MFMA_F16(ah[mt], bl[nt], ac[mt][nt]);              \
                ac[mt][nt] = MFMA_F16(al[mt], bh[nt], ac[mt][nt]);              \
            }                                                                   \
        __builtin_amdgcn_s_setprio(0);                                          \
        asm volatile("s_waitcnt lgkmcnt(0)" ::: "memory");                      \
        __builtin_amdgcn_s_barrier();                                           \
    }

__global__ __launch_bounds__(256, 2) void gemm_fused_v2(
    const _Float16* __restrict__ xhi, const _Float16* __restrict__ xlo,
    const _Float16* __restrict__ w1hi, const _Float16* __restrict__ w1lo,
    const float* __restrict__ b1, const uint32_t* __restrict__ W2Tp,
    float* __restrict__ Lp)
{
    __shared__ uint32_t smem[16384];          // 64 KB
    uint32_t* A0 = smem;                      // [128][64] halves, 16 KB
    uint32_t* B0 = smem + 4096;
    uint32_t* A1 = smem + 8192;               // double-buffer partners
    uint32_t* B1 = smem + 12288;

    const int t    = threadIdx.x;
    const int wid  = t >> 6;
    const int lane = t & 63;
    const int quad = lane >> 4;
    const int l16  = lane & 15;

    // block swizzle: groups of 8 m-blocks share one n-block (W1T slice L2 reuse)
    const int lin = blockIdx.x;               // 2048 blocks
    const int grp = lin >> 7;
    const int rem = lin & 127;
    const int m0 = (grp * 8 + (rem & 7)) * BM;
    const int n0 = (rem >> 3) * BN;

    // staging source pointers; LDS slot s of row r holds logical chunk
    // c = s ^ (r&7); c<4 -> hi array chunk c, else lo array chunk c-4.
    const _Float16* gA[4];
    const _Float16* gB[4];
    #pragma unroll
    for (int r = 0; r < 4; r++) {
        int s_lin = r * 256 + t;
        int row = s_lin >> 3;
        int c   = (s_lin & 7) ^ (row & 7);
        gA[r] = (c < 4) ? xhi  + (size_t)(m0 + row) * DIM + c * 8
                        : xlo  + (size_t)(m0 + row) * DIM + (c - 4) * 8;
        gB[r] = (c < 4) ? w1hi + (size_t)(n0 + row) * DIM + c * 8
                        : w1lo + (size_t)(n0 + row) * DIM + (c - 4) * 8;
    }

    f32x4 am[4][4], ac[4][4];
    #pragma unroll
    for (int i = 0; i < 4; i++)
        #pragma unroll
        for (int j = 0; j < 4; j++) { am[i][j] = (f32x4)0.0f; ac[i][j] = (f32x4)0.0f; }

    const int wm = (wid & 1) * 64;
    const int wn = (wid >> 1) * 64;

    // prologue: stage tile 0 into buf0 (8 loads in flight)
    #pragma unroll
    for (int r = 0; r < 4; r++) {
        const int wslot = (r * 256 + wid * 64) << 2;
        __builtin_amdgcn_global_load_lds((const GLOBAL_AS uint32_t*)gA[r],
                                         (LDS_AS uint32_t*)(A0 + wslot), 16, 0, 0);
        __builtin_amdgcn_global_load_lds((const GLOBAL_AS uint32_t*)gB[r],
                                         (LDS_AS uint32_t*)(B0 + wslot), 16, 0, 0);
        gA[r] += BKE; gB[r] += BKE;
    }

    // ---- anti-phase desync: with 512 concurrent blocks, CU-mates are
    // (lin, lin+256); offset one of them by ~half a K-step so the CU's
    // MFMA and LDS pipes overlap across blocks instead of summing. ----
    if ((lin >> 8) & 1) asm volatile("s_sleep 31");

    // 64 K-steps as 32 pairs; buffers alternate with static addresses.
    for (int kp = 0; kp < 32; kp++) {
        KSTEP(A0, B0, A1, B1, true);        // read buf0, stage tile(2kp+1)
        KSTEP(A1, B1, A0, B0, kp != 31);    // read buf1, stage tile(2kp+2)
    }

    // ---- epilogue: bias + exact GELU, pack h into swizzled LDS [128][128] ----
    uint32_t* Hs = smem;
    #pragma unroll
    for (int mt = 0; mt < 4; mt++)
        #pragma unroll
        for (int nt = 0; nt < 4; nt++) {
            const int coln = wn + nt * 16 + l16;
            const float b1v = b1[n0 + coln];
            #pragma unroll
            for (int r = 0; r < 4; r++) {
                float h = am[mt][nt][r] + ac[mt][nt][r] * INV_LO_SCALE + b1v;
                h = 0.5f * h * (1.0f + erff(h * 0.70710678118654752440f));
                const int rowm = wm + mt * 16 + quad * 4 + r;
                const int word = rowm * 128 + ((((coln >> 2) ^ (rowm & 7)) << 2) | (coln & 3));
                Hs[word] = pack_split(h);
            }
        }
    __syncthreads();

    // ---- GEMM2: logits[128 x 64] = h[128 x 128] @ W2T' (4 K=32 steps) ----
    f32x4 a2m[2][4], a2c[2][4];
    #pragma unroll
    for (int i = 0; i < 2; i++)
        #pragma unroll
        for (int j = 0; j < 4; j++) { a2m[i][j] = (f32x4)0.0f; a2c[i][j] = (f32x4)0.0f; }

    #pragma unroll
    for (int ks = 0; ks < 4; ks++) {
        half8 a2h[2], a2l[2];
        #pragma unroll
        for (int mt2 = 0; mt2 < 2; mt2++) {
            const int row = wid * 32 + mt2 * 16 + l16;
            const int sw  = row & 7;
            const int cb  = ks * 8 + quad * 2;           // k = ks*32 + quad*8 + j
            const uint4 q0 = *(const uint4*)(Hs + row * 128 + ((cb ^ sw) << 2));
            const uint4 q1 = *(const uint4*)(Hs + row * 128 + (((cb + 1) ^ sw) << 2));
            uint32_t u[8] = {q0.x, q0.y, q0.z, q0.w, q1.x, q1.y, q1.z, q1.w};
            U4H8 H, L;
            #pragma unroll
            for (int j = 0; j < 4; j++) {
                H.u[j] = (u[2 * j] & 0xffffu) | (u[2 * j + 1] << 16);
                L.u[j] = (u[2 * j] >> 16)     | (u[2 * j + 1] & 0xffff0000u);
            }
            a2h[mt2] = H.h; a2l[mt2] = L.h;
        }
        #pragma unroll
        for (int et = 0; et < 4; et++) {
            const int e = et * 16 + l16;
            const uint32_t* wp = W2Tp + (size_t)e * DIM + n0 + ks * 32 + quad * 8;
            const uint4 q0 = *(const uint4*)wp;
            const uint4 q1 = *(const uint4*)(wp + 4);
            uint32_t u[8] = {q0.x, q0.y, q0.z, q0.w, q1.x, q1.y, q1.z, q1.w};
            U4H8 H, L;
            #pragma unroll
            for (int j = 0; j < 4; j++) {
                H.u[j] = (u[2 * j] & 0xffffu) | (u[2 * j + 1] << 16);
                L.u[j] = (u[2 * j] >> 16)     | (u[2 * j + 1] & 0xffff0000u);
            }
            #pragma unroll
            for (int mt2 = 0; mt2 < 2; mt2++) {
                a2m[mt2][et] = MFMA_F16(a2h[mt2], H.h, a2m[mt2][et]);
                a2c[mt2][et] = MFMA_F16(a2h[mt2], L.h, a2c[mt2][et]);
                a2c[mt2][et] = MFMA_F16(a2l[mt2], H.h, a2c[mt2][et]);
            }
        }
    }

    #pragma unroll
    for (int mt2 = 0; mt2 < 2; mt2++)
        #pragma unroll
        for (int et = 0; et < 4; et++)
            #pragma unroll
            for (int r = 0; r < 4; r++) {
                const float lg = a2m[mt2][et][r] + a2c[mt2][et][r] * INV_LO_SCALE;
                const int rowm = m0 + wid * 32 + mt2 * 16 + quad * 4 + r;
                const int e = et * 16 + l16;
                atomicAdd(&Lp[(size_t)rowm * NEXP + e], lg);
            }
}

// ---------------------------------------------------------------------------
// packed-u32 fused GEMM (mid fallback, needs only ~21 MB ws)
// ---------------------------------------------------------------------------
__global__ __launch_bounds__(256, 2) void gemm_fused(
    const uint32_t* __restrict__ xp, const uint32_t* __restrict__ W1Tp,
    const float* __restrict__ b1, const uint32_t* __restrict__ W2Tp,
    float* __restrict__ Lp)
{
    __shared__ uint32_t smem[16384];
    uint32_t* Ap = smem;
    uint32_t* Bp = smem + 4096;

    const int t    = threadIdx.x;
    const int wid  = t >> 6;
    const int lane = t & 63;
    const int quad = lane >> 4;
    const int l16  = lane & 15;

    const int lin = blockIdx.x;
    const int grp = lin >> 7;
    const int rem = lin & 127;
    const int m0 = (grp * 8 + (rem & 7)) * BM;
    const int n0 = (rem >> 3) * BN;

    const uint32_t* gA[4];
    const uint32_t* gB[4];
    #pragma unroll
    for (int r = 0; r < 4; r++) {
        int s = r * 256 + t;
        int row = s >> 3;
        int c   = s & 7;
        int co  = (c ^ (row & 7)) << 2;
        gA[r] = xp   + (size_t)(m0 + row) * DIM + co;
        gB[r] = W1Tp + (size_t)(n0 + row) * DIM + co;
    }

    f32x4 am[4][4], ac[4][4];
    #pragma unroll
    for (int i = 0; i < 4; i++)
        #pragma unroll
        for (int j = 0; j < 4; j++) { am[i][j] = (f32x4)0.0f; ac[i][j] = (f32x4)0.0f; }

    const int wm = (wid & 1) * 64;
    const int wn = (wid >> 1) * 64;

    for (int k0 = 0; k0 < DIM; k0 += BKE) {
        #pragma unroll
        for (int r = 0; r < 4; r++) {
            const int wslot = (r * 256 + wid * 64) << 2;
            __builtin_amdgcn_global_load_lds((const GLOBAL_AS uint32_t*)gA[r],
                                             (LDS_AS uint32_t*)(Ap + wslot), 16, 0, 0);
            __builtin_amdgcn_global_load_lds((const GLOBAL_AS uint32_t*)gB[r],
                                             (LDS_AS uint32_t*)(Bp + wslot), 16, 0, 0);
            gA[r] += BKE; gB[r] += BKE;
        }
        __syncthreads();

        half8 ah[4], al[4], bh[4], bl[4];
        #pragma unroll
        for (int mt = 0; mt < 4; mt++)
            load_frag(Ap, wm + mt * 16 + l16, quad, ah[mt], al[mt]);
        #pragma unroll
        for (int nt = 0; nt < 4; nt++)
            load_frag(Bp, wn + nt * 16 + l16, quad, bh[nt], bl[nt]);

        #pragma unroll
        for (int mt = 0; mt < 4; mt++)
            #pragma unroll
            for (int nt = 0; nt < 4; nt++) {
                am[mt][nt] = MFMA_F16(ah[mt], bh[nt], am[mt][nt]);
                ac[mt][nt] = MFMA_F16(ah[mt], bl[nt], ac[mt][nt]);
                ac[mt][nt] = MFMA_F16(al[mt], bh[nt], ac[mt][nt]);
            }
        __syncthreads();
    }

    uint32_t* Hs = smem;
    #pragma unroll
    for (int mt = 0; mt < 4; mt++)
        #pragma unroll
        for (int nt = 0; nt < 4; nt++) {
            const int coln = wn + nt * 16 + l16;
            const float b1v = b1[n0 + coln];
            #pragma unroll
            for (int r = 0; r < 4; r++) {
                float h = am[mt][nt][r] + ac[mt][nt][r] * INV_LO_SCALE + b1v;
                h = 0.5f * h * (1.0f + erff(h * 0.70710678118654752440f));
                const int rowm = wm + mt * 16 + quad * 4 + r;
                const int word = rowm * 128 + ((((coln >> 2) ^ (rowm & 7)) << 2) | (coln & 3));
                Hs[word] = pack_split(h);
            }
        }
    __syncthreads();

    f32x4 a2m[2][4], a2c[2][4];
    #pragma unroll
    for (int i = 0; i < 2; i++)
        #pragma unroll
        for (int j = 0; j < 4; j++) { a2m[i][j] = (f32x4)0.0f; a2c[i][j] = (f32x4)0.0f; }

    #pragma unroll
    for (int ks = 0; ks < 4; ks++) {
        half8 a2h[2], a2l[2];
        #pragma unroll
        for (int mt2 = 0; mt2 < 2; mt2++) {
            const int row = wid * 32 + mt2 * 16 + l16;
            const int sw  = row & 7;
            const int cb  = ks * 8 + quad * 2;
            const uint4 q0 = *(const uint4*)(Hs + row * 128 + ((cb ^ sw) << 2));
            const uint4 q1 = *(const uint4*)(Hs + row * 128 + (((cb + 1) ^ sw) << 2));
            uint32_t u[8] = {q0.x, q0.y, q0.z, q0.w, q1.x, q1.y, q1.z, q1.w};
            U4H8 H, L;
            #pragma unroll
            for (int j = 0; j < 4; j++) {
                H.u[j] = (u[2 * j] & 0xffffu) | (u[2 * j + 1] << 16);
                L.u[j] = (u[2 * j] >> 16)     | (u[2 * j + 1] & 0xffff0000u);
            }
            a2h[mt2] = H.h; a2l[mt2] = L.h;
        }
        #pragma unroll
        for (int et = 0; et < 4; et++) {
            const int e = et * 16 + l16;
            const uint32_t* wp = W2Tp + (size_t)e * DIM + n0 + ks * 32 + quad * 8;
            const uint4 q0 = *(const uint4*)wp;
            const uint4 q1 = *(const uint4*)(wp + 4);
            uint32_t u[8] = {q0.x, q0.y, q0.z, q0.w, q1.x, q1.y, q1.z, q1.w};
            U4H8 H, L;
            #pragma unroll
            for (int j = 0; j < 4; j++) {
                H.u[j] = (u[2 * j] & 0xffffu) | (u[2 * j + 1] << 16);
                L.u[j] = (u[2 * j] >> 16)     | (u[2 * j + 1] & 0xffff0000u);
            }
            #pragma unroll
            for (int mt2 = 0; mt2 < 2; mt2++) {
                a2m[mt2][et] = MFMA_F16(a2h[mt2], H.h, a2m[mt2][et]);
                a2c[mt2][et] = MFMA_F16(a2h[mt2], L.h, a2c[mt2][et]);
                a2c[mt2][et] = MFMA_F16(a2l[mt2], H.h, a2c[mt2][et]);
            }
        }
    }

    #pragma unroll
    for (int mt2 = 0; mt2 < 2; mt2++)
        #pragma unroll
        for (int et = 0; et < 4; et++)
            #pragma unroll
            for (int r = 0; r < 4; r++) {
                const float lg = a2m[mt2][et][r] + a2c[mt2][et][r] * INV_LO_SCALE;
                const int rowm = m0 + wid * 32 + mt2 * 16 + quad * 4 + r;
                const int e = et * 16 + l16;
                atomicAdd(&Lp[(size_t)rowm * NEXP + e], lg);
            }
}

// ---------------------------------------------------------------------------
// routing + loss: last-block ticket pattern (loss folded into the router)
// ---------------------------------------------------------------------------
__global__ __launch_bounds__(256) void router_topk_v3(
    const float* __restrict__ Lp, const float* __restrict__ b2,
    float* __restrict__ out_rw, float* __restrict__ out_idx,
    float* __restrict__ gP, float* __restrict__ gI,
    float* __restrict__ out_loss, uint32_t* __restrict__ done)
{
    __shared__ float sP[NEXP];
    __shared__ float sI[NEXP];
    __shared__ uint32_t ticket;
    const int t = threadIdx.x;
    if (t < NEXP) { sP[t] = 0.f; sI[t] = 0.f; }
    __syncthreads();

    const int lane = t & 63;
    const int wv   = t >> 6;
    const float b2v = b2[lane];

    float accP = 0.f, accSel = 0.f;

    for (int i = 0; i < 16; i++) {
        const int tok = blockIdx.x * 64 + i * 4 + wv;
        float logit = Lp[(size_t)tok * NEXP + lane] + b2v;

        // full softmax over 64 experts (load-balance loss)
        float mx = logit;
        #pragma unroll
        for (int off = 32; off >= 1; off >>= 1) mx = fmaxf(mx, __shfl_xor(mx, off));
        float p = expf(logit - mx);
        float ps = p;
        #pragma unroll
        for (int off = 32; off >= 1; off >>= 1) ps += __shfl_xor(ps, off);
        accP += p / ps;

        // iterative top-8 argmax (min-index tiebreak)
        float cur = logit;
        float tv[TOPK]; int tix[TOPK];
        for (int k = 0; k < TOPK; k++) {
            float v = cur; int idx = lane;
            #pragma unroll
            for (int off = 32; off >= 1; off >>= 1) {
                float ov = __shfl_xor(v, off);
                int   oi = __shfl_xor(idx, off);
                if (ov > v || (ov == v && oi < idx)) { v = ov; idx = oi; }
            }
            tv[k] = v; tix[k] = idx;
            if (lane == idx) cur = -INFINITY;
        }

        float ev[TOPK], s = 0.f;
        #pragma unroll
        for (int k = 0; k < TOPK; k++) { ev[k] = expf(tv[k] - tv[0]); s += ev[k]; }
        float w = 0.f;
        #pragma unroll
        for (int k = 0; k < TOPK; k++)
            if (tix[k] == lane) { w = ev[k] / s; accSel += 1.f; }

        out_rw[(size_t)tok * NEXP + lane] = w;
        if (lane < TOPK) out_idx[(size_t)tok * TOPK + lane] = (float)tix[lane];
    }

    atomicAdd(&sP[lane], accP);
    atomicAdd(&sI[lane], accSel);
    __syncthreads();
    if (t < NEXP) { atomicAdd(&gP[t], sP[t]); atomicAdd(&gI[t], sI[t]); }

    // ---- last block computes the load-balance loss ----
    __threadfence();                         // release gP/gI contributions
    if (t == 0) ticket = atomicAdd(done, 1u);
    __syncthreads();
    if (ticket == (uint32_t)(gridDim.x - 1)) {
        __threadfence();                     // acquire
        if (t < NEXP) {
            const float inv = 1.0f / (float)N_TOK;
            float fI = atomicAdd(&gI[t], 0.0f);   // coherent read
            float fP = atomicAdd(&gP[t], 0.0f);
            float v = (fI * inv) * (fP * inv);
            #pragma unroll
            for (int off = 32; off >= 1; off >>= 1) v += __shfl_xor(v, off);
            if (t == 0) out_loss[0] = (float)NEXP * v;
        }
    }
}

extern "C" void kernel_launch(void* const* d_in, const int* in_sizes, int n_in,
                              void* d_out, int out_size, void* d_ws, size_t ws_size,
                              hipStream_t stream) {
    const float* x  = (const float*)d_in[0];
    const float* W1 = (const float*)d_in[1];
    const float* b1 = (const float*)d_in[2];
    const float* W2 = (const float*)d_in[3];
    const float* b2 = (const float*)d_in[4];

    float* out_rw   = (float*)d_out;
    float* out_idx  = out_rw + (size_t)N_TOK * NEXP;
    float* out_loss = out_idx + (size_t)N_TOK * TOPK;

    // ---- split-path ws layout (needs ~149 MiB) ----
    const size_t SZ_X   = (size_t)N_TOK * DIM * 2;      // 64 MiB per array
    const size_t SZ_W1  = (size_t)DIM * DIM * 2;        // 8 MiB per array
    const size_t OFF_XHI   = 0;
    const size_t OFF_XLO   = OFF_XHI + SZ_X;
    const size_t OFF_W1HI  = OFF_XLO + SZ_X;
    const size_t OFF_W1LO  = OFF_W1HI + SZ_W1;
    const size_t OFF_W2T   = OFF_W1LO + SZ_W1;
    const size_t OFF_LP    = OFF_W2T + (size_t)DIM * NEXP * 4;
    const size_t OFF_G     = OFF_LP + (size_t)N_TOK * NEXP * 4;
    const size_t needed_v2 = OFF_G + 2 * NEXP * 4 + 16;

    // ---- packed-path ws layout (~21 MiB) ----
    const size_t P_W1T = 0;
    const size_t P_W2T = (size_t)16 << 20;
    const size_t P_LP  = (size_t)17 << 20;
    const size_t P_G   = P_LP + (size_t)N_TOK * NEXP * 4;
    const size_t needed_p = P_G + 2 * NEXP * 4 + 16;

    if (ws_size >= needed_v2) {
        _Float16* xhi  = (_Float16*)((char*)d_ws + OFF_XHI);
        _Float16* xlo  = (_Float16*)((char*)d_ws + OFF_XLO);
        _Float16* w1hi = (_Float16*)((char*)d_ws + OFF_W1HI);
        _Float16* w1lo = (_Float16*)((char*)d_ws + OFF_W1LO);
        uint32_t* W2Tp = (uint32_t*)((char*)d_ws + OFF_W2T);
        float* Lp = (float*)((char*)d_ws + OFF_LP);
        float* gP = (float*)((char*)d_ws + OFF_G);
        float* gI = gP + NEXP;
        uint32_t* done = (uint32_t*)(gI + NEXP);

        (void)hipMemsetAsync((char*)d_ws + OFF_LP, 0,
                             (size_t)N_TOK * NEXP * 4 + 2 * NEXP * 4 + 16, stream);
        convert_all<<<CVT_XBLKS + CVT_W1BLKS + CVT_W2BLKS, 256, 0, stream>>>(
            x, W1, W2, xhi, xlo, w1hi, w1lo, W2Tp);
        gemm_fused_v2<<<(N_TOK / BM) * (DIM / BN), 256, 0, stream>>>(
            xhi, xlo, w1hi, w1lo, b1, W2Tp, Lp);
        router_topk_v3<<<N_TOK / 64, 256, 0, stream>>>(
            Lp, b2, out_rw, out_idx, gP, gI, out_loss, done);
    } else if (ws_size >= needed_p) {
        uint32_t* W1Tp = (uint32_t*)((char*)d_ws + P_W1T);
        uint32_t* W2Tp = (uint32_t*)((char*)d_ws + P_W2T);
        float* Lp = (float*)((char*)d_ws + P_LP);
        float* gP = (float*)((char*)d_ws + P_G);
        float* gI = gP + NEXP;
        uint32_t* done = (uint32_t*)(gI + NEXP);

        (void)hipMemsetAsync((char*)d_ws + P_LP, 0,
                             (size_t)N_TOK * NEXP * 4 + 2 * NEXP * 4 + 16, stream);
        convert_x_inplace<<<(N_TOK * DIM) / (256 * 4), 256, 0, stream>>>((float*)d_in[0]);
        convert_w1t_packed<<<dim3(DIM / 32, DIM / 32), 256, 0, stream>>>(W1, W1Tp);
        convert_w2t_packed<<<(NEXP * DIM) / 256, 256, 0, stream>>>(W2, W2Tp);
        gemm_fused<<<(N_TOK / BM) * (DIM / BN), 256, 0, stream>>>(
            (const uint32_t*)d_in[0], W1Tp, b1, W2Tp, Lp);
        router_topk_v3<<<N_TOK / 64, 256, 0, stream>>>(
            Lp, b2, out_rw, out_idx, gP, gI, out_loss, done);
    }
}

// Round 7
// 732.470 us; speedup vs baseline: 1.3086x; 1.0140x over previous
//
#include <hip/hip_runtime.h>
#include <math.h>
#include <stdint.h>

#define N_TOK 16384
#define DIM   2048
#define NEXP  64
#define TOPK  8

#define BM 128
#define BN 128
#define BKE 32          // k-elements per iteration

typedef _Float16 half8  __attribute__((ext_vector_type(8)));
typedef float    f32x4  __attribute__((ext_vector_type(4)));

#define GLOBAL_AS __attribute__((address_space(1)))
#define LDS_AS    __attribute__((address_space(3)))

#define LO_SCALE     4096.0f
#define INV_LO_SCALE (1.0f / 4096.0f)

// pack fp32 v -> u32: low16 = fp16(v), high16 = fp16((v - fp16(v)) * 4096)
__device__ inline uint32_t pack_split(float v) {
    _Float16 hi = (_Float16)v;
    float r = (v - (float)hi) * LO_SCALE;
    _Float16 lo = (_Float16)r;
    return (uint32_t)__builtin_bit_cast(uint16_t, hi) |
           ((uint32_t)__builtin_bit_cast(uint16_t, lo) << 16);
}

__device__ inline _Float16 split_hi(float v) { return (_Float16)v; }
__device__ inline _Float16 split_lo(float v) {
    _Float16 hi = (_Float16)v;
    return (_Float16)((v - (float)hi) * LO_SCALE);
}

union U4H8 { uint32_t u[4]; half8 h; };

// packed-u32 fragment loader (fallback path + epilogue W2 reads)
__device__ inline void load_frag(const uint32_t* base, int row, int quad,
                                 half8& hi, half8& lo) {
    const int sw = row & 7;
    const uint4 q0 = *(const uint4*)(base + row * 32 + (((quad * 2)     ^ sw) << 2));
    const uint4 q1 = *(const uint4*)(base + row * 32 + (((quad * 2 + 1) ^ sw) << 2));
    uint32_t u[8] = {q0.x, q0.y, q0.z, q0.w, q1.x, q1.y, q1.z, q1.w};
    U4H8 H, L;
    #pragma unroll
    for (int j = 0; j < 4; j++) {
        H.u[j] = (u[2 * j] & 0xffffu) | (u[2 * j + 1] << 16);
        L.u[j] = (u[2 * j] >> 16)     | (u[2 * j + 1] & 0xffff0000u);
    }
    hi = H.h; lo = L.h;
}

// split-array A fragment loader (R2-proven, 16-row frag reads):
// LDS row = 64 halves = [32 hi | 32 lo] = 8 slots of 16B; logical chunk c
// lives at slot c ^ (row&7). 16 rows x 4 quads -> 64 distinct slots,
// 2-way bank aliasing only (free, m136).
__device__ inline void load_frag2(const _Float16* base, int row, int quad,
                                  half8& hi, half8& lo) {
    const int sw = row & 7;
    hi = *(const half8*)(base + row * 64 + ((quad       ^ sw) << 3));
    lo = *(const half8*)(base + row * 64 + (((quad + 4) ^ sw) << 3));
}

// ---------------------------------------------------------------------------
// fused conversion kernel: block-range dispatch over {x-split, W1->fragment-
// major split, W2T}. W1 is stored FRAGMENT-MAJOR: 16B chunk index
//   ((((n_blk*64 + kstep)*2 + w)*8 + c)*64 + lane)
// where c<4 -> hi chunk for nt=c, c>=4 -> lo chunk for nt=c-4; lane l holds
// rows nt*16+(l&15), k = kstep*32 + (l>>4)*8 .. +8. A wave's per-step B data
// (8 KB) is fully contiguous; each of its 8 loads is a 1 KB coalesced burst.
// ---------------------------------------------------------------------------
#define CVT_XBLKS  ((N_TOK * DIM) / (256 * 8))            // 16384
#define CVT_W1BLKS ((DIM / 32) * (DIM / 32))              // 4096
#define CVT_W2BLKS ((NEXP * DIM) / 256)                   // 512

__global__ __launch_bounds__(256) void convert_all(
    const float* __restrict__ x, const float* __restrict__ W1,
    const float* __restrict__ W2,
    _Float16* __restrict__ xhi, _Float16* __restrict__ xlo,
    _Float16* __restrict__ w1f, uint32_t* __restrict__ W2Tp)
{
    const int b = blockIdx.x;
    if (b < CVT_XBLKS) {
        size_t i = ((size_t)b * 256 + threadIdx.x) * 8;
        float4 v0 = *(const float4*)(x + i);
        float4 v1 = *(const float4*)(x + i + 4);
        const float vv[8] = {v0.x, v0.y, v0.z, v0.w, v1.x, v1.y, v1.z, v1.w};
        half8 h, l;
        #pragma unroll
        for (int j = 0; j < 8; j++) { h[j] = split_hi(vv[j]); l[j] = split_lo(vv[j]); }
        *(half8*)(xhi + i) = h;
        *(half8*)(xlo + i) = l;
    } else if (b < CVT_XBLKS + CVT_W1BLKS) {
        __shared__ float s[32][33];
        const int bb = b - CVT_XBLKS;
        const int n0tile = (bb & 63) * 32, k0 = (bb >> 6) * 32;
        const int tr = threadIdx.x & 31, tc = threadIdx.x >> 5;   // 32 x 8
        #pragma unroll
        for (int r = 0; r < 4; r++) {
            int row = tc + r * 8;
            s[row][tr] = W1[(size_t)(k0 + row) * DIM + n0tile + tr];
        }
        __syncthreads();
        // write 4KB in fragment-major order: thread -> one 16B chunk slice
        const int c_sel = threadIdx.x >> 6;       // 0..3
        const int l     = threadIdx.x & 63;
        const int hi_lo = c_sel >> 1;             // 0 = hi, 1 = lo
        const int ntl   = c_sel & 1;              // which 16-row half of 32 cols
        const int row_local = ntl * 16 + (l & 15);
        const int col128 = n0tile & 127;
        const int w   = col128 >> 6;
        const int nt  = ((col128 & 63) >> 4) + ntl;
        const int c   = hi_lo * 4 + nt;
        const size_t off16 = ((((size_t)(n0tile >> 7) * 64 + (size_t)(k0 >> 5)) * 2
                               + (size_t)w) * 8 + (size_t)c) * 64 + (size_t)l;
        half8 outv;
        #pragma unroll
        for (int j = 0; j < 8; j++) {
            float v = s[(l >> 4) * 8 + j][row_local];
            outv[j] = hi_lo ? split_lo(v) : split_hi(v);
        }
        *((half8*)w1f + off16) = outv;
    } else {
        const int i = (b - CVT_XBLKS - CVT_W1BLKS) * 256 + threadIdx.x;
        const int e = i >> 11, n = i & 2047;
        W2Tp[i] = pack_split(W2[(size_t)n * NEXP + e]);
    }
}

// in-place packed converter (mid-fallback path)
__global__ __launch_bounds__(256) void convert_x_inplace(float* __restrict__ x) {
    size_t i = ((size_t)blockIdx.x * 256 + threadIdx.x) * 4;
    float4 v = *(const float4*)(x + i);
    uint4 p;
    p.x = pack_split(v.x); p.y = pack_split(v.y);
    p.z = pack_split(v.z); p.w = pack_split(v.w);
    *(uint4*)(x + i) = p;
}

__global__ __launch_bounds__(256) void convert_w1t_packed(
    const float* __restrict__ W1, uint32_t* __restrict__ W1Tp)
{
    __shared__ float s[32][33];
    const int k0 = blockIdx.y * 32, n0 = blockIdx.x * 32;
    const int tr = threadIdx.x & 31, tc = threadIdx.x >> 5;
    #pragma unroll
    for (int r = 0; r < 4; r++) {
        int row = tc + r * 8;
        s[row][tr] = W1[(size_t)(k0 + row) * DIM + n0 + tr];
    }
    __syncthreads();
    #pragma unroll
    for (int r = 0; r < 4; r++) {
        int row = tc + r * 8;
        W1Tp[(size_t)(n0 + row) * DIM + k0 + tr] = pack_split(s[tr][row]);
    }
}

__global__ __launch_bounds__(256) void convert_w2t_packed(
    const float* __restrict__ W2, uint32_t* __restrict__ W2Tp) {
    int i = blockIdx.x * 256 + threadIdx.x;   // over 64*2048
    int e = i >> 11, n = i & 2047;
    W2Tp[i] = pack_split(W2[(size_t)n * NEXP + e]);
}

// ---------------------------------------------------------------------------
// fused GEMM v9: A LDS-staged (proven path), B read as register fragments
// from FRAGMENT-MAJOR w1f (contiguous 1KB bursts, L2-hot via n-group
// swizzle), double-buffered in registers one full step ahead.
// Standing model (R2..R6): 128^2 step = MFMA 1862 + LDS-read 1536 +
// LDS-write 512 cy, pipes SUM -> 4090cy, MfmaUtil pinned ~46% under every
// schedule. This removes B from the LDS pipe entirely: reads 1536->768,
// writes 512->~300. R4's failure mode (scatter B reads, in-step latency)
// is fixed by the fragment-major layout + one-step register prefetch.
// VMEM/step = 4 A-stage + 8 B-loads = 12, all fenced between "memory"-
// clobbered asm waits -> vmcnt(12) waits exactly tile-k's 12 ops while
// tile-k+1's stay in flight across the barrier.
// ---------------------------------------------------------------------------

#define MFMA_F16(a_, b_, c_)  __builtin_amdgcn_mfma_f32_16x16x32_f16(a_, b_, c_, 0, 0, 0)

// one K-step: A from (ASrc), B from BCUR regs; optionally stage A(k+1)->ASt
// and load B(k+1)->BNXT (12 VMEM ops), counted-wait vmcnt(12).
#define KSTEP(ASrc_, ASt_, BCUR_, BNXT_, DOPRE_)                                \
    {                                                                           \
        if (DOPRE_) {                                                           \
            _Pragma("unroll")                                                   \
            for (int r = 0; r < 4; r++) {                                       \
                const int wslot = (r * 256 + wid * 64) << 2;                    \
                __builtin_amdgcn_global_load_lds(                               \
                    (const GLOBAL_AS uint32_t*)gA[r],                           \
                    (LDS_AS uint32_t*)((ASt_) + wslot), 16, 0, 0);              \
                gA[r] += BKE;                                                   \
            }                                                                   \
            _Pragma("unroll")                                                   \
            for (int c = 0; c < 8; c++)                                         \
                BNXT_[c] = *(const half8*)(bptr + c * 1024);                    \
            bptr += 16384;                                                      \
            asm volatile("s_waitcnt vmcnt(12)" ::: "memory");                   \
        } else {                                                                \
            asm volatile("s_waitcnt vmcnt(0)" ::: "memory");                    \
        }                                                                       \
        __builtin_amdgcn_s_barrier();                                           \
        half8 ah[4], al[4];                                                     \
        _Pragma("unroll")                                                       \
        for (int mt = 0; mt < 4; mt++)                                          \
            load_frag2((const _Float16*)(ASrc_), wm + mt * 16 + l16, quad,      \
                       ah[mt], al[mt]);                                         \
        __builtin_amdgcn_s_setprio(1);                                          \
        _Pragma("unroll")                                                       \
        for (int mt = 0; mt < 4; mt++)                                          \
            _Pragma("unroll")                                                   \
            for (int nt = 0; nt < 4; nt++) {                                    \
                am[mt][nt] = MFMA_F16(ah[mt], BCUR_[nt],     am[mt][nt]);       \
                ac[mt][nt] = MFMA_F16(ah[mt], BCUR_[nt + 4], ac[mt][nt]);       \
                ac[mt][nt] = MFMA_F16(al[mt], BCUR_[nt],     ac[mt][nt]);       \
            }                                                                   \
        __builtin_amdgcn_s_setprio(0);                                          \
        asm volatile("s_waitcnt lgkmcnt(0)" ::: "memory");                      \
        __builtin_amdgcn_s_barrier();   /* A buf now safe to restage */         \
    }

__global__ __launch_bounds__(256, 2) void gemm_fused_v2(
    const _Float16* __restrict__ xhi, const _Float16* __restrict__ xlo,
    const _Float16* __restrict__ w1f,
    const float* __restrict__ b1, const uint32_t* __restrict__ W2Tp,
    float* __restrict__ Lp)
{
    __shared__ uint32_t smem[16384];          // 64 KB (Hs epilogue needs it all)
    uint32_t* A0 = smem;                      // A tile [128][64] halves, 16 KB
    uint32_t* A1 = smem + 4096;               // double-buffer partner

    const int t    = threadIdx.x;
    const int wid  = t >> 6;
    const int lane = t & 63;
    const int quad = lane >> 4;
    const int l16  = lane & 15;

    // block swizzle: groups of 8 m-blocks share one n-block (W1 slice L2 reuse)
    const int lin = blockIdx.x;               // 2048 blocks
    const int grp = lin >> 7;
    const int rem = lin & 127;
    const int m0 = (grp * 8 + (rem & 7)) * BM;
    const int n0 = (rem >> 3) * BN;

    // A staging source pointers; LDS slot s of row r holds logical chunk
    // c = s ^ (r&7); c<4 -> hi array chunk c, else lo array chunk c-4.
    const _Float16* gA[4];
    #pragma unroll
    for (int r = 0; r < 4; r++) {
        int s_lin = r * 256 + t;
        int row = s_lin >> 3;
        int c   = (s_lin & 7) ^ (row & 7);
        gA[r] = (c < 4) ? xhi + (size_t)(m0 + row) * DIM + c * 8
                        : xlo + (size_t)(m0 + row) * DIM + (c - 4) * 8;
    }

    const int wm = (wid & 1) * 64;
    const int wn = (wid >> 1) * 64;

    // B fragment stream base: (n_blk*128 + w)*8192 + lane*16 bytes; each step
    // advances 16 KB. Chunk c at +c*1024.
    const char* bptr = (const char*)w1f
        + (((size_t)(n0 >> 7) * 128 + (size_t)(wid >> 1)) * 8192)
        + (size_t)lane * 16;

    f32x4 am[4][4], ac[4][4];
    #pragma unroll
    for (int i = 0; i < 4; i++)
        #pragma unroll
        for (int j = 0; j < 4; j++) { am[i][j] = (f32x4)0.0f; ac[i][j] = (f32x4)0.0f; }

    half8 bX[8], bY[8];

    // prologue: stage A(0) into A0, load B(0) into bX (12 ops in flight)
    #pragma unroll
    for (int r = 0; r < 4; r++) {
        const int wslot = (r * 256 + wid * 64) << 2;
        __builtin_amdgcn_global_load_lds((const GLOBAL_AS uint32_t*)gA[r],
                                         (LDS_AS uint32_t*)(A0 + wslot), 16, 0, 0);
        gA[r] += BKE;
    }
    #pragma unroll
    for (int c = 0; c < 8; c++)
        bX[c] = *(const half8*)(bptr + c * 1024);
    bptr += 16384;

    // 64 K-steps as 32 pairs; A LDS buffers and B register buffers ping-pong.
    for (int kp = 0; kp < 32; kp++) {
        KSTEP(A0, A1, bX, bY, true);        // step 2kp:   read A0/bX, prefetch ->A1/bY
        KSTEP(A1, A0, bY, bX, kp != 31);    // step 2kp+1: read A1/bY, prefetch ->A0/bX
    }

    // ---- epilogue: bias + exact GELU, pack h into swizzled LDS [128][128] ----
    uint32_t* Hs = smem;
    #pragma unroll
    for (int mt = 0; mt < 4; mt++)
        #pragma unroll
        for (int nt = 0; nt < 4; nt++) {
            const int coln = wn + nt * 16 + l16;
            const float b1v = b1[n0 + coln];
            #pragma unroll
            for (int r = 0; r < 4; r++) {
                float h = am[mt][nt][r] + ac[mt][nt][r] * INV_LO_SCALE + b1v;
                h = 0.5f * h * (1.0f + erff(h * 0.70710678118654752440f));
                const int rowm = wm + mt * 16 + quad * 4 + r;
                const int word = rowm * 128 + ((((coln >> 2) ^ (rowm & 7)) << 2) | (coln & 3));
                Hs[word] = pack_split(h);
            }
        }
    __syncthreads();

    // ---- GEMM2: logits[128 x 64] = h[128 x 128] @ W2T' (4 K=32 steps) ----
    f32x4 a2m[2][4], a2c[2][4];
    #pragma unroll
    for (int i = 0; i < 2; i++)
        #pragma unroll
        for (int j = 0; j < 4; j++) { a2m[i][j] = (f32x4)0.0f; a2c[i][j] = (f32x4)0.0f; }

    #pragma unroll
    for (int ks = 0; ks < 4; ks++) {
        half8 a2h[2], a2l[2];
        #pragma unroll
        for (int mt2 = 0; mt2 < 2; mt2++) {
            const int row = wid * 32 + mt2 * 16 + l16;
            const int sw  = row & 7;
            const int cb  = ks * 8 + quad * 2;           // k = ks*32 + quad*8 + j
            const uint4 q0 = *(const uint4*)(Hs + row * 128 + ((cb ^ sw) << 2));
            const uint4 q1 = *(const uint4*)(Hs + row * 128 + (((cb + 1) ^ sw) << 2));
            uint32_t u[8] = {q0.x, q0.y, q0.z, q0.w, q1.x, q1.y, q1.z, q1.w};
            U4H8 H, L;
            #pragma unroll
            for (int j = 0; j < 4; j++) {
                H.u[j] = (u[2 * j] & 0xffffu) | (u[2 * j + 1] << 16);
                L.u[j] = (u[2 * j] >> 16)     | (u[2 * j + 1] & 0xffff0000u);
            }
            a2h[mt2] = H.h; a2l[mt2] = L.h;
        }
        #pragma unroll
        for (int et = 0; et < 4; et++) {
            const int e = et * 16 + l16;
            const uint32_t* wp = W2Tp + (size_t)e * DIM + n0 + ks * 32 + quad * 8;
            const uint4 q0 = *(const uint4*)wp;
            const uint4 q1 = *(const uint4*)(wp + 4);
            uint32_t u[8] = {q0.x, q0.y, q0.z, q0.w, q1.x, q1.y, q1.z, q1.w};
            U4H8 H, L;
            #pragma unroll
            for (int j = 0; j < 4; j++) {
                H.u[j] = (u[2 * j] & 0xffffu) | (u[2 * j + 1] << 16);
                L.u[j] = (u[2 * j] >> 16)     | (u[2 * j + 1] & 0xffff0000u);
            }
            #pragma unroll
            for (int mt2 = 0; mt2 < 2; mt2++) {
                a2m[mt2][et] = MFMA_F16(a2h[mt2], H.h, a2m[mt2][et]);
                a2c[mt2][et] = MFMA_F16(a2h[mt2], L.h, a2c[mt2][et]);
                a2c[mt2][et] = MFMA_F16(a2l[mt2], H.h, a2c[mt2][et]);
            }
        }
    }

    #pragma unroll
    for (int mt2 = 0; mt2 < 2; mt2++)
        #pragma unroll
        for (int et = 0; et < 4; et++)
            #pragma unroll
            for (int r = 0; r < 4; r++) {
                const float lg = a2m[mt2][et][r] + a2c[mt2][et][r] * INV_LO_SCALE;
                const int rowm = m0 + wid * 32 + mt2 * 16 + quad * 4 + r;
                const int e = et * 16 + l16;
                atomicAdd(&Lp[(size_t)rowm * NEXP + e], lg);
            }
}

// ---------------------------------------------------------------------------
// packed-u32 fused GEMM (mid fallback, needs only ~21 MB ws)
// ---------------------------------------------------------------------------
__global__ __launch_bounds__(256, 2) void gemm_fused(
    const uint32_t* __restrict__ xp, const uint32_t* __restrict__ W1Tp,
    const float* __restrict__ b1, const uint32_t* __restrict__ W2Tp,
    float* __restrict__ Lp)
{
    __shared__ uint32_t smem[16384];
    uint32_t* Ap = smem;
    uint32_t* Bp = smem + 4096;

    const int t    = threadIdx.x;
    const int wid  = t >> 6;
    const int lane = t & 63;
    const int quad = lane >> 4;
    const int l16  = lane & 15;

    const int lin = blockIdx.x;
    const int grp = lin >> 7;
    const int rem = lin & 127;
    const int m0 = (grp * 8 + (rem & 7)) * BM;
    const int n0 = (rem >> 3) * BN;

    const uint32_t* gA[4];
    const uint32_t* gB[4];
    #pragma unroll
    for (int r = 0; r < 4; r++) {
        int s = r * 256 + t;
        int row = s >> 3;
        int c   = s & 7;
        int co  = (c ^ (row & 7)) << 2;
        gA[r] = xp   + (size_t)(m0 + row) * DIM + co;
        gB[r] = W1Tp + (size_t)(n0 + row) * DIM + co;
    }

    f32x4 am[4][4], ac[4][4];
    #pragma unroll
    for (int i = 0; i < 4; i++)
        #pragma unroll
        for (int j = 0; j < 4; j++) { am[i][j] = (f32x4)0.0f; ac[i][j] = (f32x4)0.0f; }

    const int wm = (wid & 1) * 64;
    const int wn = (wid >> 1) * 64;

    for (int k0 = 0; k0 < DIM; k0 += BKE) {
        #pragma unroll
        for (int r = 0; r < 4; r++) {
            const int wslot = (r * 256 + wid * 64) << 2;
            __builtin_amdgcn_global_load_lds((const GLOBAL_AS uint32_t*)gA[r],
                                             (LDS_AS uint32_t*)(Ap + wslot), 16, 0, 0);
            __builtin_amdgcn_global_load_lds((const GLOBAL_AS uint32_t*)gB[r],
                                             (LDS_AS uint32_t*)(Bp + wslot), 16, 0, 0);
            gA[r] += BKE; gB[r] += BKE;
        }
        __syncthreads();

        half8 ah[4], al[4], bh[4], bl[4];
        #pragma unroll
        for (int mt = 0; mt < 4; mt++)
            load_frag(Ap, wm + mt * 16 + l16, quad, ah[mt], al[mt]);
        #pragma unroll
        for (int nt = 0; nt < 4; nt++)
            load_frag(Bp, wn + nt * 16 + l16, quad, bh[nt], bl[nt]);

        #pragma unroll
        for (int mt = 0; mt < 4; mt++)
            #pragma unroll
            for (int nt = 0; nt < 4; nt++) {
                am[mt][nt] = MFMA_F16(ah[mt], bh[nt], am[mt][nt]);
                ac[mt][nt] = MFMA_F16(ah[mt], bl[nt], ac[mt][nt]);
                ac[mt][nt] = MFMA_F16(al[mt], bh[nt], ac[mt][nt]);
            }
        __syncthreads();
    }

    uint32_t* Hs = smem;
    #pragma unroll
    for (int mt = 0; mt < 4; mt++)
        #pragma unroll
        for (int nt = 0; nt < 4; nt++) {
            const int coln = wn + nt * 16 + l16;
            const float b1v = b1[n0 + coln];
            #pragma unroll
            for (int r = 0; r < 4; r++) {
                float h = am[mt][nt][r] + ac[mt][nt][r] * INV_LO_SCALE + b1v;
                h = 0.5f * h * (1.0f + erff(h * 0.70710678118654752440f));
                const int rowm = wm + mt * 16 + quad * 4 + r;
                const int word = rowm * 128 + ((((coln >> 2) ^ (rowm & 7)) << 2) | (coln & 3));
                Hs[word] = pack_split(h);
            }
        }
    __syncthreads();

    f32x4 a2m[2][4], a2c[2][4];
    #pragma unroll
    for (int i = 0; i < 2; i++)
        #pragma unroll
        for (int j = 0; j < 4; j++) { a2m[i][j] = (f32x4)0.0f; a2c[i][j] = (f32x4)0.0f; }

    #pragma unroll
    for (int ks = 0; ks < 4; ks++) {
        half8 a2h[2], a2l[2];
        #pragma unroll
        for (int mt2 = 0; mt2 < 2; mt2++) {
            const int row = wid * 32 + mt2 * 16 + l16;
            const int sw  = row & 7;
            const int cb  = ks * 8 + quad * 2;
            const uint4 q0 = *(const uint4*)(Hs + row * 128 + ((cb ^ sw) << 2));
            const uint4 q1 = *(const uint4*)(Hs + row * 128 + (((cb + 1) ^ sw) << 2));
            uint32_t u[8] = {q0.x, q0.y, q0.z, q0.w, q1.x, q1.y, q1.z, q1.w};
            U4H8 H, L;
            #pragma unroll
            for (int j = 0; j < 4; j++) {
                H.u[j] = (u[2 * j] & 0xffffu) | (u[2 * j + 1] << 16);
                L.u[j] = (u[2 * j] >> 16)     | (u[2 * j + 1] & 0xffff0000u);
            }
            a2h[mt2] = H.h; a2l[mt2] = L.h;
        }
        #pragma unroll
        for (int et = 0; et < 4; et++) {
            const int e = et * 16 + l16;
            const uint32_t* wp = W2Tp + (size_t)e * DIM + n0 + ks * 32 + quad * 8;
            const uint4 q0 = *(const uint4*)wp;
            const uint4 q1 = *(const uint4*)(wp + 4);
            uint32_t u[8] = {q0.x, q0.y, q0.z, q0.w, q1.x, q1.y, q1.z, q1.w};
            U4H8 H, L;
            #pragma unroll
            for (int j = 0; j < 4; j++) {
                H.u[j] = (u[2 * j] & 0xffffu) | (u[2 * j + 1] << 16);
                L.u[j] = (u[2 * j] >> 16)     | (u[2 * j + 1] & 0xffff0000u);
            }
            #pragma unroll
            for (int mt2 = 0; mt2 < 2; mt2++) {
                a2m[mt2][et] = MFMA_F16(a2h[mt2], H.h, a2m[mt2][et]);
                a2c[mt2][et] = MFMA_F16(a2h[mt2], L.h, a2c[mt2][et]);
                a2c[mt2][et] = MFMA_F16(a2l[mt2], H.h, a2c[mt2][et]);
            }
        }
    }

    #pragma unroll
    for (int mt2 = 0; mt2 < 2; mt2++)
        #pragma unroll
        for (int et = 0; et < 4; et++)
            #pragma unroll
            for (int r = 0; r < 4; r++) {
                const float lg = a2m[mt2][et][r] + a2c[mt2][et][r] * INV_LO_SCALE;
                const int rowm = m0 + wid * 32 + mt2 * 16 + quad * 4 + r;
                const int e = et * 16 + l16;
                atomicAdd(&Lp[(size_t)rowm * NEXP + e], lg);
            }
}

// ---------------------------------------------------------------------------
// routing + loss: last-block ticket pattern (loss folded into the router)
// ---------------------------------------------------------------------------
__global__ __launch_bounds__(256) void router_topk_v3(
    const float* __restrict__ Lp, const float* __restrict__ b2,
    float* __restrict__ out_rw, float* __restrict__ out_idx,
    float* __restrict__ gP, float* __restrict__ gI,
    float* __restrict__ out_loss, uint32_t* __restrict__ done)
{
    __shared__ float sP[NEXP];
    __shared__ float sI[NEXP];
    __shared__ uint32_t ticket;
    const int t = threadIdx.x;
    if (t < NEXP) { sP[t] = 0.f; sI[t] = 0.f; }
    __syncthreads();

    const int lane = t & 63;
    const int wv   = t >> 6;
    const float b2v = b2[lane];

    float accP = 0.f, accSel = 0.f;

    for (int i = 0; i < 16; i++) {
        const int tok = blockIdx.x * 64 + i * 4 + wv;
        float logit = Lp[(size_t)tok * NEXP + lane] + b2v;

        // full softmax over 64 experts (load-balance loss)
        float mx = logit;
        #pragma unroll
        for (int off = 32; off >= 1; off >>= 1) mx = fmaxf(mx, __shfl_xor(mx, off));
        float p = expf(logit - mx);
        float ps = p;
        #pragma unroll
        for (int off = 32; off >= 1; off >>= 1) ps += __shfl_xor(ps, off);
        accP += p / ps;

        // iterative top-8 argmax (min-index tiebreak)
        float cur = logit;
        float tv[TOPK]; int tix[TOPK];
        for (int k = 0; k < TOPK; k++) {
            float v = cur; int idx = lane;
            #pragma unroll
            for (int off = 32; off >= 1; off >>= 1) {
                float ov = __shfl_xor(v, off);
                int   oi = __shfl_xor(idx, off);
                if (ov > v || (ov == v && oi < idx)) { v = ov; idx = oi; }
            }
            tv[k] = v; tix[k] = idx;
            if (lane == idx) cur = -INFINITY;
        }

        float ev[TOPK], s = 0.f;
        #pragma unroll
        for (int k = 0; k < TOPK; k++) { ev[k] = expf(tv[k] - tv[0]); s += ev[k]; }
        float w = 0.f;
        #pragma unroll
        for (int k = 0; k < TOPK; k++)
            if (tix[k] == lane) { w = ev[k] / s; accSel += 1.f; }

        out_rw[(size_t)tok * NEXP + lane] = w;
        if (lane < TOPK) out_idx[(size_t)tok * TOPK + lane] = (float)tix[lane];
    }

    atomicAdd(&sP[lane], accP);
    atomicAdd(&sI[lane], accSel);
    __syncthreads();
    if (t < NEXP) { atomicAdd(&gP[t], sP[t]); atomicAdd(&gI[t], sI[t]); }

    // ---- last block computes the load-balance loss ----
    __threadfence();                         // release gP/gI contributions
    if (t == 0) ticket = atomicAdd(done, 1u);
    __syncthreads();
    if (ticket == (uint32_t)(gridDim.x - 1)) {
        __threadfence();                     // acquire
        if (t < NEXP) {
            const float inv = 1.0f / (float)N_TOK;
            float fI = atomicAdd(&gI[t], 0.0f);   // coherent read
            float fP = atomicAdd(&gP[t], 0.0f);
            float v = (fI * inv) * (fP * inv);
            #pragma unroll
            for (int off = 32; off >= 1; off >>= 1) v += __shfl_xor(v, off);
            if (t == 0) out_loss[0] = (float)NEXP * v;
        }
    }
}

extern "C" void kernel_launch(void* const* d_in, const int* in_sizes, int n_in,
                              void* d_out, int out_size, void* d_ws, size_t ws_size,
                              hipStream_t stream) {
    const float* x  = (const float*)d_in[0];
    const float* W1 = (const float*)d_in[1];
    const float* b1 = (const float*)d_in[2];
    const float* W2 = (const float*)d_in[3];
    const float* b2 = (const float*)d_in[4];

    float* out_rw   = (float*)d_out;
    float* out_idx  = out_rw + (size_t)N_TOK * NEXP;
    float* out_loss = out_idx + (size_t)N_TOK * TOPK;

    // ---- split-path ws layout (needs ~149 MiB) ----
    const size_t SZ_X   = (size_t)N_TOK * DIM * 2;      // 64 MiB per array
    const size_t SZ_W1F = (size_t)DIM * DIM * 4;        // 16 MiB (hi+lo frag-major)
    const size_t OFF_XHI   = 0;
    const size_t OFF_XLO   = OFF_XHI + SZ_X;
    const size_t OFF_W1F   = OFF_XLO + SZ_X;
    const size_t OFF_W2T   = OFF_W1F + SZ_W1F;
    const size_t OFF_LP    = OFF_W2T + (size_t)DIM * NEXP * 4;
    const size_t OFF_G     = OFF_LP + (size_t)N_TOK * NEXP * 4;
    const size_t needed_v2 = OFF_G + 2 * NEXP * 4 + 16;

    // ---- packed-path ws layout (~21 MiB) ----
    const size_t P_W1T = 0;
    const size_t P_W2T = (size_t)16 << 20;
    const size_t P_LP  = (size_t)17 << 20;
    const size_t P_G   = P_LP + (size_t)N_TOK * NEXP * 4;
    const size_t needed_p = P_G + 2 * NEXP * 4 + 16;

    if (ws_size >= needed_v2) {
        _Float16* xhi  = (_Float16*)((char*)d_ws + OFF_XHI);
        _Float16* xlo  = (_Float16*)((char*)d_ws + OFF_XLO);
        _Float16* w1f  = (_Float16*)((char*)d_ws + OFF_W1F);
        uint32_t* W2Tp = (uint32_t*)((char*)d_ws + OFF_W2T);
        float* Lp = (float*)((char*)d_ws + OFF_LP);
        float* gP = (float*)((char*)d_ws + OFF_G);
        float* gI = gP + NEXP;
        uint32_t* done = (uint32_t*)(gI + NEXP);

        (void)hipMemsetAsync((char*)d_ws + OFF_LP, 0,
                             (size_t)N_TOK * NEXP * 4 + 2 * NEXP * 4 + 16, stream);
        convert_all<<<CVT_XBLKS + CVT_W1BLKS + CVT_W2BLKS, 256, 0, stream>>>(
            x, W1, W2, xhi, xlo, w1f, W2Tp);
        gemm_fused_v2<<<(N_TOK / BM) * (DIM / BN), 256, 0, stream>>>(
            xhi, xlo, w1f, b1, W2Tp, Lp);
        router_topk_v3<<<N_TOK / 64, 256, 0, stream>>>(
            Lp, b2, out_rw, out_idx, gP, gI, out_loss, done);
    } else if (ws_size >= needed_p) {
        uint32_t* W1Tp = (uint32_t*)((char*)d_ws + P_W1T);
        uint32_t* W2Tp = (uint32_t*)((char*)d_ws + P_W2T);
        float* Lp = (float*)((char*)d_ws + P_LP);
        float* gP = (float*)((char*)d_ws + P_G);
        float* gI = gP + NEXP;
        uint32_t* done = (uint32_t*)(gI + NEXP);

        (void)hipMemsetAsync((char*)d_ws + P_LP, 0,
                             (size_t)N_TOK * NEXP * 4 + 2 * NEXP * 4 + 16, stream);
        convert_x_inplace<<<(N_TOK * DIM) / (256 * 4), 256, 0, stream>>>((float*)d_in[0]);
        convert_w1t_packed<<<dim3(DIM / 32, DIM / 32), 256, 0, stream>>>(W1, W1Tp);
        convert_w2t_packed<<<(NEXP * DIM) / 256, 256, 0, stream>>>(W2, W2Tp);
        gemm_fused<<<(N_TOK / BM) * (DIM / BN), 256, 0, stream>>>(
            (const uint32_t*)d_in[0], W1Tp, b1, W2Tp, Lp);
        router_topk_v3<<<N_TOK / 64, 256, 0, stream>>>(
            Lp, b2, out_rw, out_idx, gP, gI, out_loss, done);
    }
}